// Round 2
// baseline (215.200 us; speedup 1.0000x reference)
//
#include <hip/hip_runtime.h>
#include <stdint.h>

#define NGT_MAX 128
#define CAND_CAP 8192
#define CSEL_CAP 512
#define FILT_CAP 16384
#define SUB_CAP 2048

// counters (zeroed by hipMemsetAsync before k_main):
// [0]=cand cnt, [3]=gsel ticket, [4]=fg filt cnt, [5]=bg filt cnt,
// [8]=baseF (total fg), [9]=baseB (total bg)

// ---- threefry2x32 (exact JAX semantics) ----
__host__ __device__ inline void tf2x32(uint32_t k0, uint32_t k1, uint32_t c0, uint32_t c1,
                                       uint32_t& o0, uint32_t& o1) {
  uint32_t ks[3] = {k0, k1, k0 ^ k1 ^ 0x1BD11BDAu};
  uint32_t x0 = c0 + ks[0];
  uint32_t x1 = c1 + ks[1];
  const int rot[2][4] = {{13, 15, 26, 6}, {17, 29, 16, 24}};
#pragma unroll
  for (int i = 0; i < 5; ++i) {
#pragma unroll
    for (int j = 0; j < 4; ++j) {
      x0 += x1;
      int r = rot[i & 1][j];
      x1 = (x1 << r) | (x1 >> (32 - r));
      x1 ^= x0;
    }
    x0 += ks[(i + 1) % 3];
    x1 += ks[(i + 2) % 3] + (uint32_t)(i + 1);
  }
  o0 = x0; o1 = x1;
}

// Partitionable threefry: element i uses block (0,i); draw = o0^o1.
// Selection key = (bits>>9, index) lexicographic (stable argsort tiebreak).
__device__ inline uint64_t sel_key(uint32_t i, uint32_t ka, uint32_t kb) {
  uint32_t o0, o1;
  tf2x32(ka, kb, 0u, i, o0, o1);
  uint32_t bits = o0 ^ o1;
  return ((uint64_t)(bits >> 9) << 32) | (uint64_t)i;
}

__device__ inline uint32_t fmap(float v) {
  uint32_t u = __float_as_uint(v);
  return (u & 0x80000000u) ? ~u : (u | 0x80000000u);
}
__device__ inline float funmap(uint32_t m) {
  return (m & 0x80000000u) ? __uint_as_float(m & 0x7FFFFFFFu) : __uint_as_float(~m);
}

// Conservative thresholds from base counts only (baseF <= M1, M2 >= baseB-8192).
__device__ inline void cons_meta(uint32_t baseF, uint32_t baseB, uint32_t* needF,
                                 uint32_t* Tf, uint32_t* needB, uint32_t* Tb) {
  *needF = (baseF > 128u) ? 1u : 0u;
  uint64_t tf = 0, tb = 0;
  if (*needF) {
    tf = (((uint64_t)(128u * 32u)) << 23) / (uint64_t)baseF;
    if (tf > (1u << 23)) tf = (1u << 23);
  }
  uint32_t nfgmin = baseF < 128u ? baseF : 128u;
  uint32_t kbgmax = 256u - nfgmin;
  *needB = (baseB > 8192u + kbgmax) ? 1u : 0u;
  if (*needB) {
    tb = (((uint64_t)(kbgmax * 32u)) << 23) / (uint64_t)(baseB - 8192u);
    if (tb > (1u << 23)) tb = (1u << 23);
  }
  *Tf = (uint32_t)tf;
  *Tb = (uint32_t)tb;
}

__device__ __forceinline__ float iou_ref(const float4& a, float area_a, const float4& gb,
                                         float area_g) {
#pragma clang fp contract(off)
  float iw = fminf(a.z, gb.z) - fmaxf(a.x, gb.x) + 1.0f;
  float ih = fminf(a.w, gb.w) - fmaxf(a.y, gb.y) + 1.0f;
  float inter = fmaxf(iw, 0.0f) * fmaxf(ih, 0.0f);
  return inter / (area_a + area_g - inter);
}

__device__ __forceinline__ float4 tgt_ref(const float4& a, const float4& gb) {
#pragma clang fp contract(off)
  float aw = a.z - a.x + 1.0f;
  float ah = a.w - a.y + 1.0f;
  float acx = a.x + 0.5f * aw;
  float acy = a.y + 0.5f * ah;
  float gw = gb.z - gb.x + 1.0f;
  float gh = gb.w - gb.y + 1.0f;
  float gcx = gb.x + 0.5f * gw;
  float gcy = gb.y + 0.5f * gh;
  return make_float4((gcx - acx) / aw, (gcy - acy) / ah, logf(gw / aw), logf(gh / ah));
}

// IoU pass, 2 LANES PER ANCHOR: lane = 32*h + a; half h covers g in [50h, 50h+50).
// 2048 blocks x 256 threads, 128 anchors/block. Quad-DPP per g; epilogue
// row_shr:4/8 cross-quad reduce; lanes 12-15/16-row write sq[16][101].
__global__ void __launch_bounds__(256)
k_main(const float4* __restrict__ anc, const float* __restrict__ img,
       const float4* __restrict__ gt, int N, int R,
       uint32_t* __restrict__ pmax, uint32_t* __restrict__ gmaxu,
       float* __restrict__ LBL, float4* __restrict__ TGT,
       uint32_t* __restrict__ counters) {
  __shared__ float4 sgt[NGT_MAX];
  __shared__ float sarea[NGT_MAX];
  __shared__ float sq[16 * 101];  // 6.5 KB
  __shared__ uint32_t scnt[2];
  const int t = threadIdx.x, b = blockIdx.x;
  if (t < 2) scnt[t] = 0u;
  if (t < R) {
    float4 g = gt[t];
    sgt[t] = g;
    {
#pragma clang fp contract(off)
      sarea[t] = (g.z - g.x + 1.0f) * (g.w - g.y + 1.0f);
    }
  }
  for (int j = t; j < 16 * 101; j += 256) sq[j] = -1.0f;
  __syncthreads();
  const int lane = t & 63, wid = t >> 6;
  const int h = lane >> 5;       // g-half
  const int al = lane & 31;      // anchor within wave
  const int p = lane & 3;
  const int i = b * 128 + wid * 32 + al;
  const int gbase = 50 * h;
  const int Rh = R - gbase;      // live gts in this half (R=100 -> 50)
  const float H = img[0], W = img[1];
  float4 a = anc[i];
  bool inside = (a.x >= 0.0f) && (a.y >= 0.0f) && (a.z < W) && (a.w < H);
  float area_a;
  {
#pragma clang fp contract(off)
    area_a = (a.z - a.x + 1.0f) * (a.w - a.y + 1.0f);
  }
  if (!inside) area_a = __uint_as_float(0x7FC00000u);  // NaN-poison; v_max drops NaN
  const bool b1 = (p == 1), b2 = (p == 2), b3 = (p == 3);
  float part[13];
  float vmax = -1.0f;
#pragma unroll
  for (int s = 0; s < 13; ++s) {
    float v2q[4];
#pragma unroll
    for (int k = 0; k < 4; ++k) {
      const int j = 4 * s + k;
      if (j < 50 && j < Rh) {
        const int g = gbase + j;
        float4 gb = sgt[g];
        float v = iou_ref(a, area_a, gb, sarea[g]);
        vmax = fmaxf(vmax, v);
        int d1 = __builtin_amdgcn_mov_dpp(__float_as_int(v), 0xB1, 0xF, 0xF, true);
        float v1 = fmaxf(v, __int_as_float(d1));
        int d2 = __builtin_amdgcn_mov_dpp(__float_as_int(v1), 0x4E, 0xF, 0xF, true);
        v2q[k] = fmaxf(v1, __int_as_float(d2));
      } else {
        v2q[k] = -1.0f;
      }
    }
    float pp = v2q[0];
    pp = b1 ? v2q[1] : pp;
    pp = b2 ? v2q[2] : pp;
    pp = b3 ? v2q[3] : pp;
    part[s] = pp;
  }
  // per-anchor vmax: combine the two halves (lane ^ 32)
  vmax = fmaxf(vmax, __shfl_xor(vmax, 32));
  float lbl = -1.0f;
  if (inside) {
    if (vmax < 0.3f) lbl = 0.0f;
    if (vmax >= 0.7f) lbl = 1.0f;
  }
  // count each anchor once (lower 32 lanes)
  unsigned long long bf = __ballot(lbl == 1.0f) & 0xFFFFFFFFull;
  unsigned long long bb = __ballot(lbl == 0.0f) & 0xFFFFFFFFull;
  if (lane == 0) {
    atomicAdd(&scnt[0], (uint32_t)__popcll(bf));
    atomicAdd(&scnt[1], (uint32_t)__popcll(bb));
  }
  if (h == 0) {
    LBL[i] = lbl;
    float4 o = make_float4(0.f, 0.f, 0.f, 0.f);
    if (inside) {
      int idx = (int)vmax;  // faithful astype(int32) of max_ov
      idx = idx < 0 ? 0 : (idx > R - 1 ? R - 1 : idx);
      o = tgt_ref(a, sgt[idx]);
    }
    TGT[i] = o;
  }
  // epilogue: cross-quad (4 quads per 16-row) reduce in registers
#pragma unroll
  for (int s = 0; s < 13; ++s) {
    float v = part[s];
    int x = __builtin_amdgcn_mov_dpp(__float_as_int(v), 0x114, 0xF, 0xF, true);  // shr:4
    v = fmaxf(v, __int_as_float(x));
    x = __builtin_amdgcn_mov_dpp(__float_as_int(v), 0x118, 0xF, 0xF, true);      // shr:8
    v = fmaxf(v, __int_as_float(x));
    part[s] = v;
  }
  const int r = t >> 4;
  if ((t & 15) >= 12) {  // lanes 12..15 hold the 4-quad max at position p=(t&15)-12
#pragma unroll
    for (int s = 0; s < 13; ++s) {
      const int j = 4 * s + p;
      if (j < 50 && j < Rh) sq[r * 101 + gbase + j] = part[s];
    }
  }
  __syncthreads();
  if (t < R) {
    float m = -1.0f;
#pragma unroll 8
    for (int r2 = 0; r2 < 16; ++r2) m = fmaxf(m, sq[r2 * 101 + t]);  // drops NaN
    uint32_t u = fmap(m);
    pmax[b * R + t] = u;
    if (u > gmaxu[t]) atomicMax(&gmaxu[t], u);  // stale-high skip safe (monotone)
  }
  if (t == 0) {
    atomicAdd(&counters[8], scnt[0]);
    atomicAdd(&counters[9], scnt[1]);
  }
}

// LDS overlay: gather scratch dead before selection scratch comes live.
struct GPart {
  uint64_t cbuf[256];
  uint64_t bufF[256];
  uint64_t bufB[256];
  uint32_t cbufL[256];
  int tg[NGT_MAX];
  float tgm[NGT_MAX];
};
struct SPart {
  uint64_t ck[CSEL_CAP];
  uint64_t sub[SUB_CAP];
  uint32_t cc[CSEL_CAP];
  uint32_t drop[256];
  uint32_t hist[256];
  uint32_t c0s[256];
  uint32_t c1s[256];
};
union GSU { GPart g; SPart s; };

// exact k-smallest among list (all keys < T): 256-bin hist + scan + in-bin rank,
// with optional drop-index exclusion.
__device__ __forceinline__ void do_select(const uint64_t* list, uint32_t Mf, uint32_t k,
                                          uint32_t T, float* LBL, uint32_t* h,
                                          uint32_t* c0, uint32_t* c1, uint64_t* sub,
                                          uint32_t* scal, const uint32_t* drop,
                                          uint32_t nd) {
  const int t = threadIdx.x;
  if (Mf <= k) return;
  int bl = (T > 1u) ? (32 - __clz(T - 1u)) : 0;
  int shift = bl > 8 ? bl - 8 : 0;
  h[t] = 0u;
  if (t == 0) { scal[0] = 0u; scal[1] = 0u; scal[2] = 0u; }
  __syncthreads();
  for (uint32_t j = t; j < Mf; j += 256) {
    uint64_t key = list[j];
    bool skip = false;
    for (uint32_t d = 0; d < nd; ++d) skip = skip || (drop[d] == (uint32_t)key);
    if (!skip) atomicAdd(&h[((uint32_t)(key >> 32)) >> shift], 1u);
  }
  __syncthreads();
  c0[t] = h[t];
  __syncthreads();
  uint32_t* s = c0;
  uint32_t* d2 = c1;
  for (int dd = 1; dd < 256; dd <<= 1) {
    uint32_t v = s[t];
    if (t >= dd) v += s[t - dd];
    d2[t] = v;
    __syncthreads();
    uint32_t* tmp = s; s = d2; d2 = tmp;
  }
  uint32_t inc = s[t];
  uint32_t exc = inc - h[t];
  if (exc < k && inc >= k) { scal[1] = (uint32_t)t; scal[2] = k - exc; }
  __syncthreads();
  const uint32_t binb = scal[1], rneed = scal[2];
  for (uint32_t j = t; j < Mf; j += 256) {
    uint64_t key = list[j];
    bool skip = false;
    for (uint32_t d = 0; d < nd; ++d) skip = skip || (drop[d] == (uint32_t)key);
    if (skip) continue;
    uint32_t bin = ((uint32_t)(key >> 32)) >> shift;
    if (bin > binb) {
      LBL[(uint32_t)key] = -1.0f;
    } else if (bin == binb) {
      uint32_t pp = atomicAdd(&scal[0], 1u);
      if (pp < SUB_CAP) sub[pp] = key;
    }
  }
  __syncthreads();
  uint32_t c = scal[0] < SUB_CAP ? scal[0] : SUB_CAP;
  for (uint32_t s2 = t; s2 < c; s2 += 256) {
    uint64_t key = sub[s2];
    uint32_t rank = 0u;
    for (uint32_t j = 0; j < c; ++j) rank += (sub[j] < key) ? 1u : 0u;
    if (rank >= rneed) LBL[(uint32_t)key] = -1.0f;
  }
  __syncthreads();
}

// Merged gather+select: tie detection via the two pmax rows vs gmax + bit-exact
// IoU recompute; provisional keep-all flip; conservative prefilter; block-staged
// appends. Last block (device ticket) runs the exact selection in-place.
__global__ void __launch_bounds__(256)
k_gsel(const float4* __restrict__ anc, const float* __restrict__ img,
       const float4* __restrict__ gt, int N, int R,
       const uint32_t* __restrict__ pmax, const uint32_t* __restrict__ gmaxu,
       float* __restrict__ LBL,
       uint64_t* __restrict__ candList, uint32_t* __restrict__ candLbl,
       uint64_t* __restrict__ listF, uint64_t* __restrict__ listB,
       uint32_t* __restrict__ counters,
       uint32_t k1a, uint32_t k1b, uint32_t k2a, uint32_t k2b,
       uint32_t k3a, uint32_t k3b) {
  __shared__ GSU u;
  __shared__ float4 sgt[NGT_MAX];
  __shared__ float sarea[NGT_MAX];
  __shared__ uint32_t sbase[2];
  __shared__ uint32_t scal[8];
  __shared__ int tcnt;
  __shared__ uint32_t cC, cF, cB, oC, oF, oB, sticket;
  const int t = threadIdx.x, b = blockIdx.x;
  const int NBg = gridDim.x;
  if (t == 0) {
    tcnt = 0; cC = 0u; cF = 0u; cB = 0u;
    sbase[0] = counters[8];
    sbase[1] = counters[9];
  }
  if (t < R) {
    float4 g = gt[t];
    sgt[t] = g;
    {
#pragma clang fp contract(off)
      sarea[t] = (g.z - g.x + 1.0f) * (g.w - g.y + 1.0f);
    }
  }
  __syncthreads();
  const uint32_t baseF = sbase[0];
  const uint32_t baseB = sbase[1];
  uint32_t needF, Tf, needB, Tb;
  cons_meta(baseF, baseB, &needF, &Tf, &needB, &Tb);
  if (t < R) {
    uint32_t gm = gmaxu[t];
    uint32_t pm0 = pmax[(2 * b) * R + t];
    uint32_t pm1 = pmax[(2 * b + 1) * R + t];
    if (pm0 == gm || pm1 == gm) {
      int pp = atomicAdd(&tcnt, 1);
      u.g.tg[pp] = t;
      u.g.tgm[pp] = funmap(gm);
    }
  }
  __syncthreads();
  const int C0 = tcnt;
  const int i = b * 256 + t;
  const float H = img[0], W = img[1];
  float old = LBL[i];
  bool isc = false;
  if (C0 > 0) {
    float4 a = anc[i];
    bool inside = (a.x >= 0.0f) && (a.y >= 0.0f) && (a.z < W) && (a.w < H);
    if (inside) {
      float area_a;
      {
#pragma clang fp contract(off)
        area_a = (a.z - a.x + 1.0f) * (a.w - a.y + 1.0f);
      }
      for (int j = 0; j < C0; ++j) {
        int g = u.g.tg[j];
        float v = iou_ref(a, area_a, sgt[g], sarea[g]);  // bit-identical to k_main
        isc = isc || (v == u.g.tgm[j]);
      }
    }
  }
  if (isc) {
    uint32_t code = (old == 1.0f) ? 2u : ((old == 0.0f) ? 1u : 0u);
    uint32_t pp = atomicAdd(&cC, 1u);
    u.g.cbuf[pp] = sel_key((uint32_t)i, k1a, k1b);
    u.g.cbufL[pp] = code;
  }
  float l1 = isc ? 1.0f : old;  // provisional keep-all (selection fixes if C > R)
  float out = l1;
  if (l1 == 1.0f) {
    uint64_t key = sel_key((uint32_t)i, k2a, k2b);
    if (needF && (uint32_t)(key >> 32) >= Tf) {
      out = -1.0f;
    } else {
      uint32_t pp = atomicAdd(&cF, 1u);
      u.g.bufF[pp] = key;
    }
  } else if (l1 == 0.0f) {
    uint64_t key = sel_key((uint32_t)i, k3a, k3b);
    if (needB && (uint32_t)(key >> 32) >= Tb) {
      out = -1.0f;
    } else {
      uint32_t pp = atomicAdd(&cB, 1u);
      u.g.bufB[pp] = key;
    }
  }
  LBL[i] = out;
  __syncthreads();
  if (t == 0 && cC) oC = atomicAdd(&counters[0], cC);
  if (t == 64 && cF) oF = atomicAdd(&counters[4], cF);
  if (t == 128 && cB) oB = atomicAdd(&counters[5], cB);
  __syncthreads();
  for (uint32_t j = t; j < cC; j += 256) {
    uint32_t pp = oC + j;
    if (pp < CAND_CAP) { candList[pp] = u.g.cbuf[j]; candLbl[pp] = u.g.cbufL[j]; }
  }
  for (uint32_t j = t; j < cF; j += 256) {
    uint32_t pp = oF + j;
    if (pp < FILT_CAP) listF[pp] = u.g.bufF[j];
  }
  for (uint32_t j = t; j < cB; j += 256) {
    uint32_t pp = oB + j;
    if (pp < FILT_CAP) listB[pp] = u.g.bufB[j];
  }
  // ---- last-block ticket: only the final arriver proceeds to selection ----
  __threadfence();  // release: make this block's global writes visible
  __syncthreads();
  if (t == 0) sticket = atomicAdd(&counters[3], 1u);
  __syncthreads();
  if (sticket != (uint32_t)(NBg - 1)) return;
  __threadfence();  // acquire: see all other blocks' released writes

  // ---------------- selection (former k_sel), single block ----------------
  if (t < 8) scal[t] = 0u;
  uint32_t C = atomicAdd(&counters[0], 0u);
  if (C > CSEL_CAP) C = CSEL_CAP;
  for (uint32_t s = t; s < C; s += 256) { u.s.ck[s] = candList[s]; u.s.cc[s] = candLbl[s]; }
  __syncthreads();
  const uint32_t MfB0raw = atomicAdd(&counters[5], 0u);
  const uint32_t MfB0 = MfB0raw < FILT_CAP ? MfB0raw : FILT_CAP;
  for (uint32_t e = t; e < C; e += 256) {
    uint64_t key = u.s.ck[e];
    bool keep = true;
    if (C > (uint32_t)R) {
      uint32_t rank = 0;
      for (uint32_t j = 0; j < C; ++j) rank += (u.s.ck[j] < key) ? 1u : 0u;
      keep = (rank < (uint32_t)R);
    }
    uint32_t code = u.s.cc[e];
    uint32_t idx = (uint32_t)key;
    if (keep) {
      if (code != 2u) atomicAdd(&scal[4], 1u);  // fgflips
      if (code == 1u) atomicAdd(&scal[5], 1u);  // bgflips
    } else if (code != 2u) {
      uint32_t pp = atomicAdd(&scal[3], 1u);  // nDrop
      if (pp < 256) u.s.drop[pp] = idx;
      if (code == 0u) {
        LBL[idx] = -1.0f;
      } else {  // restore to bg flow
        uint64_t key3 = sel_key(idx, k3a, k3b);
        if (needB && (uint32_t)(key3 >> 32) >= Tb) {
          LBL[idx] = -1.0f;
        } else {
          uint32_t qq = atomicAdd(&scal[6], 1u);  // nAddB
          if (MfB0 + qq < FILT_CAP) listB[MfB0 + qq] = key3;
          LBL[idx] = 0.0f;
        }
      }
    }
  }
  __syncthreads();
  const uint32_t fgflips = scal[4], bgflips = scal[5];
  const uint32_t nDrop = scal[3] < 256u ? scal[3] : 256u;
  const uint32_t nAdd = scal[6];
  const uint32_t M1 = baseF + fgflips;
  const uint32_t M2 = baseB - bgflips;
  const uint32_t nfg = M1 < 128u ? M1 : 128u;
  const uint32_t kbg = 256u - nfg;
  if (M1 > 128u) {
    uint32_t MfFraw = atomicAdd(&counters[4], 0u);
    uint32_t MfF = MfFraw < FILT_CAP ? MfFraw : FILT_CAP;
    uint32_t TF = needF ? Tf : (1u << 23);
    do_select(listF, MfF, 128u, TF, LBL, u.s.hist, u.s.c0s, u.s.c1s, u.s.sub, scal,
              u.s.drop, nDrop);
  }
  if (M2 > kbg) {
    uint32_t MfB = MfB0 + nAdd;
    if (MfB > FILT_CAP) MfB = FILT_CAP;
    uint32_t TB = needB ? Tb : (1u << 23);
    do_select(listB, MfB, kbg, TB, LBL, u.s.hist, u.s.c0s, u.s.c1s, u.s.sub, scal,
              u.s.drop, 0u);
  }
}

extern "C" void kernel_launch(void* const* d_in, const int* in_sizes, int n_in,
                              void* d_out, int out_size, void* d_ws, size_t ws_size,
                              hipStream_t stream) {
  (void)n_in; (void)out_size; (void)ws_size;
  const int N = in_sizes[0] / 4;  // 262144 anchors (multiple of 256)
  const int R = in_sizes[2] / 4;  // 100 gt boxes (51..100 assumed by the h-split)
  const int NBm = N / 128;        // k_main blocks (2048)
  const int NBg = N / 256;        // k_gsel blocks (1024)
  const float4* anc = (const float4*)d_in[0];
  const float* img = (const float*)d_in[1];
  const float4* gtb = (const float4*)d_in[2];
  float* LBL = (float*)d_out;
  float4* TGT = (float4*)((float*)d_out + N);

  uint8_t* ws = (uint8_t*)d_ws;
  uint32_t* counters = (uint32_t*)ws;                  // 16 u32 (memset below)
  uint32_t* gmaxu = (uint32_t*)(ws + 512);             // 128 u32 (poison-tolerant)
  uint32_t* candLbl = (uint32_t*)(ws + 16384);         // CAND_CAP u32 (32 KB)
  uint32_t* pmax = (uint32_t*)(ws + 65536);            // NBm*R u32 (~820 KB)
  size_t off = 65536 + (size_t)NBm * R * 4;
  off = (off + 7) & ~(size_t)7;
  uint64_t* candList = (uint64_t*)(ws + off);
  uint64_t* listF = (uint64_t*)(ws + off + CAND_CAP * 8);
  uint64_t* listB = (uint64_t*)(ws + off + CAND_CAP * 8 + FILT_CAP * 8);

  // Partitionable jax.random.split(key(42), 3): key_j = threefry((0,42),(0,j))
  uint32_t k1a, k1b, k2a, k2b, k3a, k3b;
  tf2x32(0u, 42u, 0u, 0u, k1a, k1b);
  tf2x32(0u, 42u, 0u, 1u, k2a, k2b);
  tf2x32(0u, 42u, 0u, 2u, k3a, k3b);

  hipMemsetAsync(counters, 0, 64, stream);  // async, graph-capturable
  k_main<<<NBm, 256, 0, stream>>>(anc, img, gtb, N, R, pmax, gmaxu, LBL, TGT,
                                  counters);
  k_gsel<<<NBg, 256, 0, stream>>>(anc, img, gtb, N, R, pmax, gmaxu, LBL,
                                  candList, candLbl, listF, listB, counters,
                                  k1a, k1b, k2a, k2b, k3a, k3b);
}

// Round 3
// 161.044 us; speedup vs baseline: 1.3363x; 1.3363x over previous
//
#include <hip/hip_runtime.h>
#include <stdint.h>

#define NGT_MAX 128
#define CAND_CAP 8192
#define CSEL_CAP 512
#define FILT_CAP 16384
#define SUB_CAP 2048

// counters (zeroed by hipMemsetAsync before k_main):
// [0]=cand cnt, [4]=fg filt cnt, [5]=bg filt cnt,
// [8]=baseF (total fg), [9]=baseB (total bg)

// ---- threefry2x32 (exact JAX semantics) ----
__host__ __device__ inline void tf2x32(uint32_t k0, uint32_t k1, uint32_t c0, uint32_t c1,
                                       uint32_t& o0, uint32_t& o1) {
  uint32_t ks[3] = {k0, k1, k0 ^ k1 ^ 0x1BD11BDAu};
  uint32_t x0 = c0 + ks[0];
  uint32_t x1 = c1 + ks[1];
  const int rot[2][4] = {{13, 15, 26, 6}, {17, 29, 16, 24}};
#pragma unroll
  for (int i = 0; i < 5; ++i) {
#pragma unroll
    for (int j = 0; j < 4; ++j) {
      x0 += x1;
      int r = rot[i & 1][j];
      x1 = (x1 << r) | (x1 >> (32 - r));
      x1 ^= x0;
    }
    x0 += ks[(i + 1) % 3];
    x1 += ks[(i + 2) % 3] + (uint32_t)(i + 1);
  }
  o0 = x0; o1 = x1;
}

// Partitionable threefry: element i uses block (0,i); draw = o0^o1.
// Selection key = (bits>>9, index) lexicographic (stable argsort tiebreak).
__device__ inline uint64_t sel_key(uint32_t i, uint32_t ka, uint32_t kb) {
  uint32_t o0, o1;
  tf2x32(ka, kb, 0u, i, o0, o1);
  uint32_t bits = o0 ^ o1;
  return ((uint64_t)(bits >> 9) << 32) | (uint64_t)i;
}

__device__ inline uint32_t fmap(float v) {
  uint32_t u = __float_as_uint(v);
  return (u & 0x80000000u) ? ~u : (u | 0x80000000u);
}
__device__ inline float funmap(uint32_t m) {
  return (m & 0x80000000u) ? __uint_as_float(m & 0x7FFFFFFFu) : __uint_as_float(~m);
}

// Conservative thresholds from base counts only (baseF <= M1, M2 >= baseB-8192).
__device__ inline void cons_meta(uint32_t baseF, uint32_t baseB, uint32_t* needF,
                                 uint32_t* Tf, uint32_t* needB, uint32_t* Tb) {
  *needF = (baseF > 128u) ? 1u : 0u;
  uint64_t tf = 0, tb = 0;
  if (*needF) {
    tf = (((uint64_t)(128u * 32u)) << 23) / (uint64_t)baseF;
    if (tf > (1u << 23)) tf = (1u << 23);
  }
  uint32_t nfgmin = baseF < 128u ? baseF : 128u;
  uint32_t kbgmax = 256u - nfgmin;
  *needB = (baseB > 8192u + kbgmax) ? 1u : 0u;
  if (*needB) {
    tb = (((uint64_t)(kbgmax * 32u)) << 23) / (uint64_t)(baseB - 8192u);
    if (tb > (1u << 23)) tb = (1u << 23);
  }
  *Tf = (uint32_t)tf;
  *Tb = (uint32_t)tb;
}

__device__ __forceinline__ float iou_ref(const float4& a, float area_a, const float4& gb,
                                         float area_g) {
#pragma clang fp contract(off)
  float iw = fminf(a.z, gb.z) - fmaxf(a.x, gb.x) + 1.0f;
  float ih = fminf(a.w, gb.w) - fmaxf(a.y, gb.y) + 1.0f;
  float inter = fmaxf(iw, 0.0f) * fmaxf(ih, 0.0f);
  return inter / (area_a + area_g - inter);
}

__device__ __forceinline__ float4 tgt_ref(const float4& a, const float4& gb) {
#pragma clang fp contract(off)
  float aw = a.z - a.x + 1.0f;
  float ah = a.w - a.y + 1.0f;
  float acx = a.x + 0.5f * aw;
  float acy = a.y + 0.5f * ah;
  float gw = gb.z - gb.x + 1.0f;
  float gh = gb.w - gb.y + 1.0f;
  float gcx = gb.x + 0.5f * gw;
  float gcy = gb.y + 0.5f * gh;
  return make_float4((gcx - acx) / aw, (gcy - acy) / ah, logf(gw / aw), logf(gh / ah));
}

// IoU pass, 2 LANES PER ANCHOR: lane = 32*h + a; half h covers g in [50h, 50h+50).
// 2048 blocks x 256 threads, 128 anchors/block -> 8192 waves. Quad-DPP per g;
// epilogue row_shr:4/8 cross-quad reduce; lanes 12-15/16-row write sq[16][101].
__global__ void __launch_bounds__(256)
k_main(const float4* __restrict__ anc, const float* __restrict__ img,
       const float4* __restrict__ gt, int N, int R,
       uint32_t* __restrict__ pmax, uint32_t* __restrict__ gmaxu,
       float* __restrict__ LBL, float4* __restrict__ TGT,
       uint32_t* __restrict__ counters) {
  __shared__ float4 sgt[NGT_MAX];
  __shared__ float sarea[NGT_MAX];
  __shared__ float sq[16 * 101];  // 6.5 KB
  __shared__ uint32_t scnt[2];
  const int t = threadIdx.x, b = blockIdx.x;
  if (t < 2) scnt[t] = 0u;
  if (t < R) {
    float4 g = gt[t];
    sgt[t] = g;
    {
#pragma clang fp contract(off)
      sarea[t] = (g.z - g.x + 1.0f) * (g.w - g.y + 1.0f);
    }
  }
  for (int j = t; j < 16 * 101; j += 256) sq[j] = -1.0f;
  __syncthreads();
  const int lane = t & 63, wid = t >> 6;
  const int h = lane >> 5;       // g-half
  const int al = lane & 31;      // anchor within wave
  const int p = lane & 3;
  const int i = b * 128 + wid * 32 + al;
  const int gbase = 50 * h;
  const int Rh = R - gbase;      // live gts in this half (R=100 -> 50)
  const float H = img[0], W = img[1];
  float4 a = anc[i];
  bool inside = (a.x >= 0.0f) && (a.y >= 0.0f) && (a.z < W) && (a.w < H);
  float area_a;
  {
#pragma clang fp contract(off)
    area_a = (a.z - a.x + 1.0f) * (a.w - a.y + 1.0f);
  }
  if (!inside) area_a = __uint_as_float(0x7FC00000u);  // NaN-poison; v_max drops NaN
  const bool b1 = (p == 1), b2 = (p == 2), b3 = (p == 3);
  float part[13];
  float vmax = -1.0f;
#pragma unroll
  for (int s = 0; s < 13; ++s) {
    float v2q[4];
#pragma unroll
    for (int k = 0; k < 4; ++k) {
      const int j = 4 * s + k;
      if (j < 50 && j < Rh) {
        const int g = gbase + j;
        float4 gb = sgt[g];
        float v = iou_ref(a, area_a, gb, sarea[g]);
        vmax = fmaxf(vmax, v);
        int d1 = __builtin_amdgcn_mov_dpp(__float_as_int(v), 0xB1, 0xF, 0xF, true);
        float v1 = fmaxf(v, __int_as_float(d1));
        int d2 = __builtin_amdgcn_mov_dpp(__float_as_int(v1), 0x4E, 0xF, 0xF, true);
        v2q[k] = fmaxf(v1, __int_as_float(d2));
      } else {
        v2q[k] = -1.0f;
      }
    }
    float pp = v2q[0];
    pp = b1 ? v2q[1] : pp;
    pp = b2 ? v2q[2] : pp;
    pp = b3 ? v2q[3] : pp;
    part[s] = pp;
  }
  // per-anchor vmax: combine the two halves (lane ^ 32)
  vmax = fmaxf(vmax, __shfl_xor(vmax, 32));
  float lbl = -1.0f;
  if (inside) {
    if (vmax < 0.3f) lbl = 0.0f;
    if (vmax >= 0.7f) lbl = 1.0f;
  }
  // count each anchor once (lower 32 lanes)
  unsigned long long bf = __ballot(lbl == 1.0f) & 0xFFFFFFFFull;
  unsigned long long bb = __ballot(lbl == 0.0f) & 0xFFFFFFFFull;
  if (lane == 0) {
    atomicAdd(&scnt[0], (uint32_t)__popcll(bf));
    atomicAdd(&scnt[1], (uint32_t)__popcll(bb));
  }
  if (h == 0) {
    LBL[i] = lbl;
    float4 o = make_float4(0.f, 0.f, 0.f, 0.f);
    if (inside) {
      int idx = (int)vmax;  // faithful astype(int32) of max_ov
      idx = idx < 0 ? 0 : (idx > R - 1 ? R - 1 : idx);
      o = tgt_ref(a, sgt[idx]);
    }
    TGT[i] = o;
  }
  // epilogue: cross-quad (4 quads per 16-row) reduce in registers
#pragma unroll
  for (int s = 0; s < 13; ++s) {
    float v = part[s];
    int x = __builtin_amdgcn_mov_dpp(__float_as_int(v), 0x114, 0xF, 0xF, true);  // shr:4
    v = fmaxf(v, __int_as_float(x));
    x = __builtin_amdgcn_mov_dpp(__float_as_int(v), 0x118, 0xF, 0xF, true);      // shr:8
    v = fmaxf(v, __int_as_float(x));
    part[s] = v;
  }
  const int r = t >> 4;
  if ((t & 15) >= 12) {  // lanes 12..15 hold the 4-quad max at position p=(t&15)-12
#pragma unroll
    for (int s = 0; s < 13; ++s) {
      const int j = 4 * s + p;
      if (j < 50 && j < Rh) sq[r * 101 + gbase + j] = part[s];
    }
  }
  __syncthreads();
  if (t < R) {
    float m = -1.0f;
#pragma unroll 8
    for (int r2 = 0; r2 < 16; ++r2) m = fmaxf(m, sq[r2 * 101 + t]);  // drops NaN
    uint32_t u = fmap(m);
    pmax[b * R + t] = u;
    if (u > gmaxu[t]) atomicMax(&gmaxu[t], u);  // stale-high skip safe (monotone)
  }
  if (t == 0) {
    atomicAdd(&counters[8], scnt[0]);  // baseF
    atomicAdd(&counters[9], scnt[1]);  // baseB
  }
}

// Merged cand+gather (256 anchors/block = 2 main-blocks): tie detection via the two
// pmax rows vs gmax + bit-exact IoU recompute; provisional keep-all flip; conservative
// prefilter; block-staged appends. Base counts come from counters[8,9] (two scalar
// loads) instead of a per-block pmeta re-reduction.
__global__ void __launch_bounds__(256)
k_gather(const float4* __restrict__ anc, const float* __restrict__ img,
         const float4* __restrict__ gt, int N, int R,
         const uint32_t* __restrict__ pmax, const uint32_t* __restrict__ gmaxu,
         float* __restrict__ LBL,
         uint64_t* __restrict__ candList, uint32_t* __restrict__ candLbl,
         uint64_t* __restrict__ listF, uint64_t* __restrict__ listB,
         uint32_t* __restrict__ counters,
         uint32_t k1a, uint32_t k1b, uint32_t k2a, uint32_t k2b,
         uint32_t k3a, uint32_t k3b) {
  __shared__ int tg[NGT_MAX];
  __shared__ float tgm[NGT_MAX];
  __shared__ float4 sgt[NGT_MAX];
  __shared__ float sarea[NGT_MAX];
  __shared__ uint64_t cbuf[256];
  __shared__ uint32_t cbufL[256];
  __shared__ uint64_t bufF[256], bufB[256];
  __shared__ uint32_t sbase[2];
  __shared__ uint32_t cC, cF, cB, oC, oF, oB;
  __shared__ int tcnt;
  const int t = threadIdx.x, b = blockIdx.x;
  if (t == 0) {
    tcnt = 0; cC = 0u; cF = 0u; cB = 0u;
    sbase[0] = counters[8];
    sbase[1] = counters[9];
  }
  if (t < R) {
    float4 g = gt[t];
    sgt[t] = g;
    {
#pragma clang fp contract(off)
      sarea[t] = (g.z - g.x + 1.0f) * (g.w - g.y + 1.0f);
    }
  }
  __syncthreads();
  const uint32_t baseF = sbase[0];
  const uint32_t baseB = sbase[1];
  uint32_t needF, Tf, needB, Tb;
  cons_meta(baseF, baseB, &needF, &Tf, &needB, &Tb);
  if (t < R) {
    uint32_t gm = gmaxu[t];
    uint32_t pm0 = pmax[(2 * b) * R + t];
    uint32_t pm1 = pmax[(2 * b + 1) * R + t];
    if (pm0 == gm || pm1 == gm) {
      int pp = atomicAdd(&tcnt, 1);
      tg[pp] = t;
      tgm[pp] = funmap(gm);
    }
  }
  __syncthreads();
  const int C0 = tcnt;
  const int i = b * 256 + t;
  const float H = img[0], W = img[1];
  float old = LBL[i];
  bool isc = false;
  if (C0 > 0) {
    float4 a = anc[i];
    bool inside = (a.x >= 0.0f) && (a.y >= 0.0f) && (a.z < W) && (a.w < H);
    if (inside) {
      float area_a;
      {
#pragma clang fp contract(off)
        area_a = (a.z - a.x + 1.0f) * (a.w - a.y + 1.0f);
      }
      for (int j = 0; j < C0; ++j) {
        int g = tg[j];
        float v = iou_ref(a, area_a, sgt[g], sarea[g]);  // bit-identical to k_main
        isc = isc || (v == tgm[j]);
      }
    }
  }
  if (isc) {
    uint32_t code = (old == 1.0f) ? 2u : ((old == 0.0f) ? 1u : 0u);
    uint32_t pp = atomicAdd(&cC, 1u);
    cbuf[pp] = sel_key((uint32_t)i, k1a, k1b);
    cbufL[pp] = code;
  }
  float l1 = isc ? 1.0f : old;  // provisional keep-all (k_sel fixes if C > R)
  float out = l1;
  if (l1 == 1.0f) {
    uint64_t key = sel_key((uint32_t)i, k2a, k2b);
    if (needF && (uint32_t)(key >> 32) >= Tf) {
      out = -1.0f;
    } else {
      uint32_t pp = atomicAdd(&cF, 1u);
      bufF[pp] = key;
    }
  } else if (l1 == 0.0f) {
    uint64_t key = sel_key((uint32_t)i, k3a, k3b);
    if (needB && (uint32_t)(key >> 32) >= Tb) {
      out = -1.0f;
    } else {
      uint32_t pp = atomicAdd(&cB, 1u);
      bufB[pp] = key;
    }
  }
  LBL[i] = out;
  __syncthreads();
  if (t == 0 && cC) oC = atomicAdd(&counters[0], cC);
  if (t == 64 && cF) oF = atomicAdd(&counters[4], cF);
  if (t == 128 && cB) oB = atomicAdd(&counters[5], cB);
  __syncthreads();
  for (uint32_t j = t; j < cC; j += 256) {
    uint32_t pp = oC + j;
    if (pp < CAND_CAP) { candList[pp] = cbuf[j]; candLbl[pp] = cbufL[j]; }
  }
  for (uint32_t j = t; j < cF; j += 256) {
    uint32_t pp = oF + j;
    if (pp < FILT_CAP) listF[pp] = bufF[j];
  }
  for (uint32_t j = t; j < cB; j += 256) {
    uint32_t pp = oB + j;
    if (pp < FILT_CAP) listB[pp] = bufB[j];
  }
}

// exact k-smallest among list (all keys < T): 256-bin hist + scan + in-bin rank,
// with optional drop-index exclusion.
__device__ __forceinline__ void do_select(const uint64_t* list, uint32_t Mf, uint32_t k,
                                          uint32_t T, float* LBL, uint32_t* h,
                                          uint32_t* c0, uint32_t* c1, uint64_t* sub,
                                          uint32_t* scal, const uint32_t* drop,
                                          uint32_t nd) {
  const int t = threadIdx.x;
  if (Mf <= k) return;
  int bl = (T > 1u) ? (32 - __clz(T - 1u)) : 0;
  int shift = bl > 8 ? bl - 8 : 0;
  h[t] = 0u;
  if (t == 0) { scal[0] = 0u; scal[1] = 0u; scal[2] = 0u; }
  __syncthreads();
  for (uint32_t j = t; j < Mf; j += 256) {
    uint64_t key = list[j];
    bool skip = false;
    for (uint32_t d = 0; d < nd; ++d) skip = skip || (drop[d] == (uint32_t)key);
    if (!skip) atomicAdd(&h[((uint32_t)(key >> 32)) >> shift], 1u);
  }
  __syncthreads();
  c0[t] = h[t];
  __syncthreads();
  uint32_t* s = c0;
  uint32_t* d2 = c1;
  for (int dd = 1; dd < 256; dd <<= 1) {
    uint32_t v = s[t];
    if (t >= dd) v += s[t - dd];
    d2[t] = v;
    __syncthreads();
    uint32_t* tmp = s; s = d2; d2 = tmp;
  }
  uint32_t inc = s[t];
  uint32_t exc = inc - h[t];
  if (exc < k && inc >= k) { scal[1] = (uint32_t)t; scal[2] = k - exc; }
  __syncthreads();
  const uint32_t binb = scal[1], rneed = scal[2];
  for (uint32_t j = t; j < Mf; j += 256) {
    uint64_t key = list[j];
    bool skip = false;
    for (uint32_t d = 0; d < nd; ++d) skip = skip || (drop[d] == (uint32_t)key);
    if (skip) continue;
    uint32_t bin = ((uint32_t)(key >> 32)) >> shift;
    if (bin > binb) {
      LBL[(uint32_t)key] = -1.0f;
    } else if (bin == binb) {
      uint32_t pp = atomicAdd(&scal[0], 1u);
      if (pp < SUB_CAP) sub[pp] = key;
    }
  }
  __syncthreads();
  uint32_t c = scal[0] < SUB_CAP ? scal[0] : SUB_CAP;
  for (uint32_t s2 = t; s2 < c; s2 += 256) {
    uint64_t key = sub[s2];
    uint32_t rank = 0u;
    for (uint32_t j = 0; j < c; ++j) rank += (sub[j] < key) ? 1u : 0u;
    if (rank >= rneed) LBL[(uint32_t)key] = -1.0f;
  }
  __syncthreads();
}

// Single block: exact meta from counters; undo wrong provisional flips if C > R;
// exact top-k selects.
__global__ void __launch_bounds__(256)
k_sel(float* __restrict__ LBL, uint64_t* __restrict__ listF,
      uint64_t* __restrict__ listB, const uint64_t* __restrict__ candList,
      const uint32_t* __restrict__ candLbl,
      uint32_t* __restrict__ counters, int R,
      uint32_t k3a, uint32_t k3b) {
  __shared__ uint64_t ck[CSEL_CAP];
  __shared__ uint32_t cc[CSEL_CAP];
  __shared__ uint32_t drop[256];
  __shared__ uint32_t h[256], c0s[256], c1s[256];
  __shared__ uint64_t sub[SUB_CAP];
  __shared__ uint32_t scal[8];
  const int t = threadIdx.x;
  if (t < 8) scal[t] = 0u;
  const uint32_t baseF = counters[8];
  const uint32_t baseB = counters[9];
  uint32_t needFc, TfC, needBc, TbC;
  cons_meta(baseF, baseB, &needFc, &TfC, &needBc, &TbC);
  uint32_t C = counters[0];
  if (C > CSEL_CAP) C = CSEL_CAP;
  for (uint32_t s = t; s < C; s += 256) { ck[s] = candList[s]; cc[s] = candLbl[s]; }
  __syncthreads();
  const uint32_t MfB0 = counters[5] < FILT_CAP ? counters[5] : FILT_CAP;
  for (uint32_t e = t; e < C; e += 256) {
    uint64_t key = ck[e];
    bool keep = true;
    if (C > (uint32_t)R) {
      uint32_t rank = 0;
      for (uint32_t j = 0; j < C; ++j) rank += (ck[j] < key) ? 1u : 0u;
      keep = (rank < (uint32_t)R);
    }
    uint32_t code = cc[e];
    uint32_t idx = (uint32_t)key;
    if (keep) {
      if (code != 2u) atomicAdd(&scal[4], 1u);  // fgflips
      if (code == 1u) atomicAdd(&scal[5], 1u);  // bgflips
    } else if (code != 2u) {
      uint32_t pp = atomicAdd(&scal[3], 1u);  // nDrop
      if (pp < 256) drop[pp] = idx;
      if (code == 0u) {
        LBL[idx] = -1.0f;
      } else {  // restore to bg flow
        uint64_t key3 = sel_key(idx, k3a, k3b);
        if (needBc && (uint32_t)(key3 >> 32) >= TbC) {
          LBL[idx] = -1.0f;
        } else {
          uint32_t qq = atomicAdd(&scal[6], 1u);  // nAddB
          if (MfB0 + qq < FILT_CAP) listB[MfB0 + qq] = key3;
          LBL[idx] = 0.0f;
        }
      }
    }
  }
  __syncthreads();
  const uint32_t fgflips = scal[4], bgflips = scal[5];
  const uint32_t nDrop = scal[3] < 256u ? scal[3] : 256u;
  const uint32_t nAdd = scal[6];
  const uint32_t M1 = baseF + fgflips;
  const uint32_t M2 = baseB - bgflips;
  const uint32_t nfg = M1 < 128u ? M1 : 128u;
  const uint32_t kbg = 256u - nfg;
  if (M1 > 128u) {
    uint32_t MfF = counters[4] < FILT_CAP ? counters[4] : FILT_CAP;
    uint32_t TF = needFc ? TfC : (1u << 23);
    do_select(listF, MfF, 128u, TF, LBL, h, c0s, c1s, sub, scal, drop, nDrop);
  }
  if (M2 > kbg) {
    uint32_t MfB = MfB0 + nAdd;
    if (MfB > FILT_CAP) MfB = FILT_CAP;
    uint32_t TB = needBc ? TbC : (1u << 23);
    do_select(listB, MfB, kbg, TB, LBL, h, c0s, c1s, sub, scal, drop, 0u);
  }
}

extern "C" void kernel_launch(void* const* d_in, const int* in_sizes, int n_in,
                              void* d_out, int out_size, void* d_ws, size_t ws_size,
                              hipStream_t stream) {
  (void)n_in; (void)out_size; (void)ws_size;
  const int N = in_sizes[0] / 4;  // 262144 anchors (multiple of 256)
  const int R = in_sizes[2] / 4;  // 100 gt boxes (51..100 assumed by the h-split)
  const int NBm = N / 128;        // k_main blocks (2048)
  const int NBg = N / 256;        // k_gather blocks (1024)
  const float4* anc = (const float4*)d_in[0];
  const float* img = (const float*)d_in[1];
  const float4* gtb = (const float4*)d_in[2];
  float* LBL = (float*)d_out;
  float4* TGT = (float4*)((float*)d_out + N);

  uint8_t* ws = (uint8_t*)d_ws;
  uint32_t* counters = (uint32_t*)ws;                  // 16 u32 (memset below)
  uint32_t* gmaxu = (uint32_t*)(ws + 512);             // 128 u32 (poison-tolerant)
  uint32_t* candLbl = (uint32_t*)(ws + 16384);         // CAND_CAP u32 (32 KB)
  uint32_t* pmax = (uint32_t*)(ws + 65536);            // NBm*R u32 (~820 KB)
  size_t off = 65536 + (size_t)NBm * R * 4;
  off = (off + 7) & ~(size_t)7;
  uint64_t* candList = (uint64_t*)(ws + off);
  uint64_t* listF = (uint64_t*)(ws + off + CAND_CAP * 8);
  uint64_t* listB = (uint64_t*)(ws + off + CAND_CAP * 8 + FILT_CAP * 8);

  // Partitionable jax.random.split(key(42), 3): key_j = threefry((0,42),(0,j))
  uint32_t k1a, k1b, k2a, k2b, k3a, k3b;
  tf2x32(0u, 42u, 0u, 0u, k1a, k1b);
  tf2x32(0u, 42u, 0u, 1u, k2a, k2b);
  tf2x32(0u, 42u, 0u, 2u, k3a, k3b);

  hipMemsetAsync(counters, 0, 64, stream);  // async, graph-capturable
  k_main<<<NBm, 256, 0, stream>>>(anc, img, gtb, N, R, pmax, gmaxu, LBL, TGT,
                                  counters);
  k_gather<<<NBg, 256, 0, stream>>>(anc, img, gtb, N, R, pmax, gmaxu, LBL,
                                    candList, candLbl, listF, listB, counters,
                                    k1a, k1b, k2a, k2b, k3a, k3b);
  k_sel<<<1, 256, 0, stream>>>(LBL, listF, listB, candList, candLbl, counters,
                               R, k3a, k3b);
}

// Round 4
// 139.212 us; speedup vs baseline: 1.5458x; 1.1568x over previous
//
#include <hip/hip_runtime.h>
#include <stdint.h>

#define NGT_MAX 128
#define CAND_CAP 8192
#define CSEL_CAP 512
#define FILT_CAP 16384
#define SUB_CAP 2048

// ws layout (first 4 KB zeroed by hipMemsetAsync):
//   counters @0: [0]=cand cnt, [4]=fg filt cnt, [5]=bg filt cnt
//   gmaxu    @512: 128 u32 (zero-init; fmap never returns 0)
//   acc      @1024: 32 slots x 64B; slot s holds {fgCount, bgCount} at acc[16s..16s+1]
//            (one slot per line -> k_main block b adds into slot b&31: 64 RMW/addr)

// ---- threefry2x32 (exact JAX semantics) ----
__host__ __device__ inline void tf2x32(uint32_t k0, uint32_t k1, uint32_t c0, uint32_t c1,
                                       uint32_t& o0, uint32_t& o1) {
  uint32_t ks[3] = {k0, k1, k0 ^ k1 ^ 0x1BD11BDAu};
  uint32_t x0 = c0 + ks[0];
  uint32_t x1 = c1 + ks[1];
  const int rot[2][4] = {{13, 15, 26, 6}, {17, 29, 16, 24}};
#pragma unroll
  for (int i = 0; i < 5; ++i) {
#pragma unroll
    for (int j = 0; j < 4; ++j) {
      x0 += x1;
      int r = rot[i & 1][j];
      x1 = (x1 << r) | (x1 >> (32 - r));
      x1 ^= x0;
    }
    x0 += ks[(i + 1) % 3];
    x1 += ks[(i + 2) % 3] + (uint32_t)(i + 1);
  }
  o0 = x0; o1 = x1;
}

// Partitionable threefry: element i uses block (0,i); draw = o0^o1.
// Selection key = (bits>>9, index) lexicographic (stable argsort tiebreak).
__device__ inline uint64_t sel_key(uint32_t i, uint32_t ka, uint32_t kb) {
  uint32_t o0, o1;
  tf2x32(ka, kb, 0u, i, o0, o1);
  uint32_t bits = o0 ^ o1;
  return ((uint64_t)(bits >> 9) << 32) | (uint64_t)i;
}

__device__ inline uint32_t fmap(float v) {
  uint32_t u = __float_as_uint(v);
  return (u & 0x80000000u) ? ~u : (u | 0x80000000u);
}
__device__ inline float funmap(uint32_t m) {
  return (m & 0x80000000u) ? __uint_as_float(m & 0x7FFFFFFFu) : __uint_as_float(~m);
}

// 32-slot spread-accumulator reduce: first wave sums acc slots, result -> sbase[0..1].
// Call with all 256 threads; follow with __syncthreads() at the call site.
__device__ __forceinline__ void acc_reduce(const uint32_t* __restrict__ acc,
                                           uint32_t* sbase) {
  const int t = threadIdx.x;
  if (t < 64) {
    uint32_t f = 0u, g2 = 0u;
    if (t < 32) { f = acc[t * 16]; g2 = acc[t * 16 + 1]; }
#pragma unroll
    for (int o = 32; o > 0; o >>= 1) {
      f += __shfl_down(f, o);
      g2 += __shfl_down(g2, o);
    }
    if (t == 0) { sbase[0] = f; sbase[1] = g2; }
  }
}

// Conservative thresholds from base counts only (baseF <= M1, M2 >= baseB-8192).
__device__ inline void cons_meta(uint32_t baseF, uint32_t baseB, uint32_t* needF,
                                 uint32_t* Tf, uint32_t* needB, uint32_t* Tb) {
  *needF = (baseF > 128u) ? 1u : 0u;
  uint64_t tf = 0, tb = 0;
  if (*needF) {
    tf = (((uint64_t)(128u * 32u)) << 23) / (uint64_t)baseF;
    if (tf > (1u << 23)) tf = (1u << 23);
  }
  uint32_t nfgmin = baseF < 128u ? baseF : 128u;
  uint32_t kbgmax = 256u - nfgmin;
  *needB = (baseB > 8192u + kbgmax) ? 1u : 0u;
  if (*needB) {
    tb = (((uint64_t)(kbgmax * 32u)) << 23) / (uint64_t)(baseB - 8192u);
    if (tb > (1u << 23)) tb = (1u << 23);
  }
  *Tf = (uint32_t)tf;
  *Tb = (uint32_t)tb;
}

__device__ __forceinline__ float iou_ref(const float4& a, float area_a, const float4& gb,
                                         float area_g) {
#pragma clang fp contract(off)
  float iw = fminf(a.z, gb.z) - fmaxf(a.x, gb.x) + 1.0f;
  float ih = fminf(a.w, gb.w) - fmaxf(a.y, gb.y) + 1.0f;
  float inter = fmaxf(iw, 0.0f) * fmaxf(ih, 0.0f);
  return inter / (area_a + area_g - inter);
}

__device__ __forceinline__ float4 tgt_ref(const float4& a, const float4& gb) {
#pragma clang fp contract(off)
  float aw = a.z - a.x + 1.0f;
  float ah = a.w - a.y + 1.0f;
  float acx = a.x + 0.5f * aw;
  float acy = a.y + 0.5f * ah;
  float gw = gb.z - gb.x + 1.0f;
  float gh = gb.w - gb.y + 1.0f;
  float gcx = gb.x + 0.5f * gw;
  float gcy = gb.y + 0.5f * gh;
  return make_float4((gcx - acx) / aw, (gcy - acy) / ah, logf(gw / aw), logf(gh / ah));
}

// IoU pass, 2 LANES PER ANCHOR: lane = 32*h + a; half h covers g in [50h, 50h+50).
// 2048 blocks x 256 threads, 128 anchors/block -> 8192 waves. Quad-DPP per g;
// epilogue row_shr:4/8 cross-quad reduce; lanes 12-15/16-row write sq[16][101].
__global__ void __launch_bounds__(256)
k_main(const float4* __restrict__ anc, const float* __restrict__ img,
       const float4* __restrict__ gt, int N, int R,
       uint32_t* __restrict__ pmax, uint32_t* __restrict__ gmaxu,
       float* __restrict__ LBL, float4* __restrict__ TGT,
       uint32_t* __restrict__ acc) {
  __shared__ float4 sgt[NGT_MAX];
  __shared__ float sarea[NGT_MAX];
  __shared__ float sq[16 * 101];  // 6.5 KB
  __shared__ uint32_t scnt[2];
  const int t = threadIdx.x, b = blockIdx.x;
  if (t < 2) scnt[t] = 0u;
  if (t < R) {
    float4 g = gt[t];
    sgt[t] = g;
    {
#pragma clang fp contract(off)
      sarea[t] = (g.z - g.x + 1.0f) * (g.w - g.y + 1.0f);
    }
  }
  for (int j = t; j < 16 * 101; j += 256) sq[j] = -1.0f;
  __syncthreads();
  const int lane = t & 63, wid = t >> 6;
  const int h = lane >> 5;       // g-half
  const int al = lane & 31;      // anchor within wave
  const int p = lane & 3;
  const int i = b * 128 + wid * 32 + al;
  const int gbase = 50 * h;
  const int Rh = R - gbase;      // live gts in this half (R=100 -> 50)
  const float H = img[0], W = img[1];
  float4 a = anc[i];
  bool inside = (a.x >= 0.0f) && (a.y >= 0.0f) && (a.z < W) && (a.w < H);
  float area_a;
  {
#pragma clang fp contract(off)
    area_a = (a.z - a.x + 1.0f) * (a.w - a.y + 1.0f);
  }
  if (!inside) area_a = __uint_as_float(0x7FC00000u);  // NaN-poison; v_max drops NaN
  const bool b1 = (p == 1), b2 = (p == 2), b3 = (p == 3);
  float part[13];
  float vmax = -1.0f;
#pragma unroll
  for (int s = 0; s < 13; ++s) {
    float v2q[4];
#pragma unroll
    for (int k = 0; k < 4; ++k) {
      const int j = 4 * s + k;
      if (j < 50 && j < Rh) {
        const int g = gbase + j;
        float4 gb = sgt[g];
        float v = iou_ref(a, area_a, gb, sarea[g]);
        vmax = fmaxf(vmax, v);
        int d1 = __builtin_amdgcn_mov_dpp(__float_as_int(v), 0xB1, 0xF, 0xF, true);
        float v1 = fmaxf(v, __int_as_float(d1));
        int d2 = __builtin_amdgcn_mov_dpp(__float_as_int(v1), 0x4E, 0xF, 0xF, true);
        v2q[k] = fmaxf(v1, __int_as_float(d2));
      } else {
        v2q[k] = -1.0f;
      }
    }
    float pp = v2q[0];
    pp = b1 ? v2q[1] : pp;
    pp = b2 ? v2q[2] : pp;
    pp = b3 ? v2q[3] : pp;
    part[s] = pp;
  }
  // per-anchor vmax: combine the two halves (lane ^ 32)
  vmax = fmaxf(vmax, __shfl_xor(vmax, 32));
  float lbl = -1.0f;
  if (inside) {
    if (vmax < 0.3f) lbl = 0.0f;
    if (vmax >= 0.7f) lbl = 1.0f;
  }
  // count each anchor once (lower 32 lanes)
  unsigned long long bf = __ballot(lbl == 1.0f) & 0xFFFFFFFFull;
  unsigned long long bb = __ballot(lbl == 0.0f) & 0xFFFFFFFFull;
  if (lane == 0) {
    atomicAdd(&scnt[0], (uint32_t)__popcll(bf));
    atomicAdd(&scnt[1], (uint32_t)__popcll(bb));
  }
  if (h == 0) {
    LBL[i] = lbl;
    float4 o = make_float4(0.f, 0.f, 0.f, 0.f);
    if (inside) {
      int idx = (int)vmax;  // faithful astype(int32) of max_ov
      idx = idx < 0 ? 0 : (idx > R - 1 ? R - 1 : idx);
      o = tgt_ref(a, sgt[idx]);
    }
    TGT[i] = o;
  }
  // epilogue: cross-quad (4 quads per 16-row) reduce in registers
#pragma unroll
  for (int s = 0; s < 13; ++s) {
    float v = part[s];
    int x = __builtin_amdgcn_mov_dpp(__float_as_int(v), 0x114, 0xF, 0xF, true);  // shr:4
    v = fmaxf(v, __int_as_float(x));
    x = __builtin_amdgcn_mov_dpp(__float_as_int(v), 0x118, 0xF, 0xF, true);      // shr:8
    v = fmaxf(v, __int_as_float(x));
    part[s] = v;
  }
  const int r = t >> 4;
  if ((t & 15) >= 12) {  // lanes 12..15 hold the 4-quad max at position p=(t&15)-12
#pragma unroll
    for (int s = 0; s < 13; ++s) {
      const int j = 4 * s + p;
      if (j < 50 && j < Rh) sq[r * 101 + gbase + j] = part[s];
    }
  }
  __syncthreads();
  if (t < R) {
    float m = -1.0f;
#pragma unroll 8
    for (int r2 = 0; r2 < 16; ++r2) m = fmaxf(m, sq[r2 * 101 + t]);  // drops NaN
    uint32_t u = fmap(m);
    pmax[b * R + t] = u;
    if (u > gmaxu[t]) atomicMax(&gmaxu[t], u);  // stale-low guard read: still correct
  }
  if (t == 0) {
    const uint32_t slot = (uint32_t)(b & 31) * 16u;  // own 64B line per slot
    atomicAdd(&acc[slot], scnt[0]);      // fg partial
    atomicAdd(&acc[slot + 1], scnt[1]);  // bg partial
  }
}

// Merged cand+gather (256 anchors/block = 2 main-blocks): tie detection via the two
// pmax rows vs gmax + bit-exact IoU recompute; provisional keep-all flip; conservative
// prefilter; block-staged appends. Base counts from the 32-slot accumulator (one
// wave-reduce) instead of a per-block pmeta re-reduction.
__global__ void __launch_bounds__(256)
k_gather(const float4* __restrict__ anc, const float* __restrict__ img,
         const float4* __restrict__ gt, int N, int R,
         const uint32_t* __restrict__ pmax, const uint32_t* __restrict__ gmaxu,
         float* __restrict__ LBL,
         uint64_t* __restrict__ candList, uint32_t* __restrict__ candLbl,
         uint64_t* __restrict__ listF, uint64_t* __restrict__ listB,
         uint32_t* __restrict__ counters, const uint32_t* __restrict__ acc,
         uint32_t k1a, uint32_t k1b, uint32_t k2a, uint32_t k2b,
         uint32_t k3a, uint32_t k3b) {
  __shared__ int tg[NGT_MAX];
  __shared__ float tgm[NGT_MAX];
  __shared__ float4 sgt[NGT_MAX];
  __shared__ float sarea[NGT_MAX];
  __shared__ uint64_t cbuf[256];
  __shared__ uint32_t cbufL[256];
  __shared__ uint64_t bufF[256], bufB[256];
  __shared__ uint32_t sbase[2];
  __shared__ uint32_t cC, cF, cB, oC, oF, oB;
  __shared__ int tcnt;
  const int t = threadIdx.x, b = blockIdx.x;
  if (t == 0) { tcnt = 0; cC = 0u; cF = 0u; cB = 0u; }
  acc_reduce(acc, sbase);
  if (t < R) {
    float4 g = gt[t];
    sgt[t] = g;
    {
#pragma clang fp contract(off)
      sarea[t] = (g.z - g.x + 1.0f) * (g.w - g.y + 1.0f);
    }
  }
  __syncthreads();
  const uint32_t baseF = sbase[0];
  const uint32_t baseB = sbase[1];
  uint32_t needF, Tf, needB, Tb;
  cons_meta(baseF, baseB, &needF, &Tf, &needB, &Tb);
  if (t < R) {
    uint32_t gm = gmaxu[t];
    uint32_t pm0 = pmax[(2 * b) * R + t];
    uint32_t pm1 = pmax[(2 * b + 1) * R + t];
    if (pm0 == gm || pm1 == gm) {
      int pp = atomicAdd(&tcnt, 1);
      tg[pp] = t;
      tgm[pp] = funmap(gm);
    }
  }
  __syncthreads();
  const int C0 = tcnt;
  const int i = b * 256 + t;
  const float H = img[0], W = img[1];
  float old = LBL[i];
  bool isc = false;
  if (C0 > 0) {
    float4 a = anc[i];
    bool inside = (a.x >= 0.0f) && (a.y >= 0.0f) && (a.z < W) && (a.w < H);
    if (inside) {
      float area_a;
      {
#pragma clang fp contract(off)
        area_a = (a.z - a.x + 1.0f) * (a.w - a.y + 1.0f);
      }
      for (int j = 0; j < C0; ++j) {
        int g = tg[j];
        float v = iou_ref(a, area_a, sgt[g], sarea[g]);  // bit-identical to k_main
        isc = isc || (v == tgm[j]);
      }
    }
  }
  if (isc) {
    uint32_t code = (old == 1.0f) ? 2u : ((old == 0.0f) ? 1u : 0u);
    uint32_t pp = atomicAdd(&cC, 1u);
    cbuf[pp] = sel_key((uint32_t)i, k1a, k1b);
    cbufL[pp] = code;
  }
  float l1 = isc ? 1.0f : old;  // provisional keep-all (k_sel fixes if C > R)
  float out = l1;
  if (l1 == 1.0f) {
    uint64_t key = sel_key((uint32_t)i, k2a, k2b);
    if (needF && (uint32_t)(key >> 32) >= Tf) {
      out = -1.0f;
    } else {
      uint32_t pp = atomicAdd(&cF, 1u);
      bufF[pp] = key;
    }
  } else if (l1 == 0.0f) {
    uint64_t key = sel_key((uint32_t)i, k3a, k3b);
    if (needB && (uint32_t)(key >> 32) >= Tb) {
      out = -1.0f;
    } else {
      uint32_t pp = atomicAdd(&cB, 1u);
      bufB[pp] = key;
    }
  }
  LBL[i] = out;
  __syncthreads();
  if (t == 0 && cC) oC = atomicAdd(&counters[0], cC);
  if (t == 64 && cF) oF = atomicAdd(&counters[4], cF);
  if (t == 128 && cB) oB = atomicAdd(&counters[5], cB);
  __syncthreads();
  for (uint32_t j = t; j < cC; j += 256) {
    uint32_t pp = oC + j;
    if (pp < CAND_CAP) { candList[pp] = cbuf[j]; candLbl[pp] = cbufL[j]; }
  }
  for (uint32_t j = t; j < cF; j += 256) {
    uint32_t pp = oF + j;
    if (pp < FILT_CAP) listF[pp] = bufF[j];
  }
  for (uint32_t j = t; j < cB; j += 256) {
    uint32_t pp = oB + j;
    if (pp < FILT_CAP) listB[pp] = bufB[j];
  }
}

// exact k-smallest among list (all keys < T): 256-bin hist + scan + in-bin rank,
// with optional drop-index exclusion.
__device__ __forceinline__ void do_select(const uint64_t* list, uint32_t Mf, uint32_t k,
                                          uint32_t T, float* LBL, uint32_t* h,
                                          uint32_t* c0, uint32_t* c1, uint64_t* sub,
                                          uint32_t* scal, const uint32_t* drop,
                                          uint32_t nd) {
  const int t = threadIdx.x;
  if (Mf <= k) return;
  int bl = (T > 1u) ? (32 - __clz(T - 1u)) : 0;
  int shift = bl > 8 ? bl - 8 : 0;
  h[t] = 0u;
  if (t == 0) { scal[0] = 0u; scal[1] = 0u; scal[2] = 0u; }
  __syncthreads();
  for (uint32_t j = t; j < Mf; j += 256) {
    uint64_t key = list[j];
    bool skip = false;
    for (uint32_t d = 0; d < nd; ++d) skip = skip || (drop[d] == (uint32_t)key);
    if (!skip) atomicAdd(&h[((uint32_t)(key >> 32)) >> shift], 1u);
  }
  __syncthreads();
  c0[t] = h[t];
  __syncthreads();
  uint32_t* s = c0;
  uint32_t* d2 = c1;
  for (int dd = 1; dd < 256; dd <<= 1) {
    uint32_t v = s[t];
    if (t >= dd) v += s[t - dd];
    d2[t] = v;
    __syncthreads();
    uint32_t* tmp = s; s = d2; d2 = tmp;
  }
  uint32_t inc = s[t];
  uint32_t exc = inc - h[t];
  if (exc < k && inc >= k) { scal[1] = (uint32_t)t; scal[2] = k - exc; }
  __syncthreads();
  const uint32_t binb = scal[1], rneed = scal[2];
  for (uint32_t j = t; j < Mf; j += 256) {
    uint64_t key = list[j];
    bool skip = false;
    for (uint32_t d = 0; d < nd; ++d) skip = skip || (drop[d] == (uint32_t)key);
    if (skip) continue;
    uint32_t bin = ((uint32_t)(key >> 32)) >> shift;
    if (bin > binb) {
      LBL[(uint32_t)key] = -1.0f;
    } else if (bin == binb) {
      uint32_t pp = atomicAdd(&scal[0], 1u);
      if (pp < SUB_CAP) sub[pp] = key;
    }
  }
  __syncthreads();
  uint32_t c = scal[0] < SUB_CAP ? scal[0] : SUB_CAP;
  for (uint32_t s2 = t; s2 < c; s2 += 256) {
    uint64_t key = sub[s2];
    uint32_t rank = 0u;
    for (uint32_t j = 0; j < c; ++j) rank += (sub[j] < key) ? 1u : 0u;
    if (rank >= rneed) LBL[(uint32_t)key] = -1.0f;
  }
  __syncthreads();
}

// Single block: exact meta from the 32-slot accumulator; undo wrong provisional
// flips if C > R; exact top-k selects.
__global__ void __launch_bounds__(256)
k_sel(float* __restrict__ LBL, uint64_t* __restrict__ listF,
      uint64_t* __restrict__ listB, const uint64_t* __restrict__ candList,
      const uint32_t* __restrict__ candLbl,
      uint32_t* __restrict__ counters, const uint32_t* __restrict__ acc, int R,
      uint32_t k3a, uint32_t k3b) {
  __shared__ uint64_t ck[CSEL_CAP];
  __shared__ uint32_t cc[CSEL_CAP];
  __shared__ uint32_t drop[256];
  __shared__ uint32_t h[256], c0s[256], c1s[256];
  __shared__ uint64_t sub[SUB_CAP];
  __shared__ uint32_t scal[8];
  __shared__ uint32_t sbase[2];
  const int t = threadIdx.x;
  if (t < 8) scal[t] = 0u;
  acc_reduce(acc, sbase);
  uint32_t C = counters[0];
  if (C > CSEL_CAP) C = CSEL_CAP;
  for (uint32_t s = t; s < C; s += 256) { ck[s] = candList[s]; cc[s] = candLbl[s]; }
  __syncthreads();
  const uint32_t baseF = sbase[0];
  const uint32_t baseB = sbase[1];
  uint32_t needFc, TfC, needBc, TbC;
  cons_meta(baseF, baseB, &needFc, &TfC, &needBc, &TbC);
  const uint32_t MfB0 = counters[5] < FILT_CAP ? counters[5] : FILT_CAP;
  for (uint32_t e = t; e < C; e += 256) {
    uint64_t key = ck[e];
    bool keep = true;
    if (C > (uint32_t)R) {
      uint32_t rank = 0;
      for (uint32_t j = 0; j < C; ++j) rank += (ck[j] < key) ? 1u : 0u;
      keep = (rank < (uint32_t)R);
    }
    uint32_t code = cc[e];
    uint32_t idx = (uint32_t)key;
    if (keep) {
      if (code != 2u) atomicAdd(&scal[4], 1u);  // fgflips
      if (code == 1u) atomicAdd(&scal[5], 1u);  // bgflips
    } else if (code != 2u) {
      uint32_t pp = atomicAdd(&scal[3], 1u);  // nDrop
      if (pp < 256) drop[pp] = idx;
      if (code == 0u) {
        LBL[idx] = -1.0f;
      } else {  // restore to bg flow
        uint64_t key3 = sel_key(idx, k3a, k3b);
        if (needBc && (uint32_t)(key3 >> 32) >= TbC) {
          LBL[idx] = -1.0f;
        } else {
          uint32_t qq = atomicAdd(&scal[6], 1u);  // nAddB
          if (MfB0 + qq < FILT_CAP) listB[MfB0 + qq] = key3;
          LBL[idx] = 0.0f;
        }
      }
    }
  }
  __syncthreads();
  const uint32_t fgflips = scal[4], bgflips = scal[5];
  const uint32_t nDrop = scal[3] < 256u ? scal[3] : 256u;
  const uint32_t nAdd = scal[6];
  const uint32_t M1 = baseF + fgflips;
  const uint32_t M2 = baseB - bgflips;
  const uint32_t nfg = M1 < 128u ? M1 : 128u;
  const uint32_t kbg = 256u - nfg;
  if (M1 > 128u) {
    uint32_t MfF = counters[4] < FILT_CAP ? counters[4] : FILT_CAP;
    uint32_t TF = needFc ? TfC : (1u << 23);
    do_select(listF, MfF, 128u, TF, LBL, h, c0s, c1s, sub, scal, drop, nDrop);
  }
  if (M2 > kbg) {
    uint32_t MfB = MfB0 + nAdd;
    if (MfB > FILT_CAP) MfB = FILT_CAP;
    uint32_t TB = needBc ? TbC : (1u << 23);
    do_select(listB, MfB, kbg, TB, LBL, h, c0s, c1s, sub, scal, drop, 0u);
  }
}

extern "C" void kernel_launch(void* const* d_in, const int* in_sizes, int n_in,
                              void* d_out, int out_size, void* d_ws, size_t ws_size,
                              hipStream_t stream) {
  (void)n_in; (void)out_size; (void)ws_size;
  const int N = in_sizes[0] / 4;  // 262144 anchors (multiple of 256)
  const int R = in_sizes[2] / 4;  // 100 gt boxes (51..100 assumed by the h-split)
  const int NBm = N / 128;        // k_main blocks (2048)
  const int NBg = N / 256;        // k_gather blocks (1024)
  const float4* anc = (const float4*)d_in[0];
  const float* img = (const float*)d_in[1];
  const float4* gtb = (const float4*)d_in[2];
  float* LBL = (float*)d_out;
  float4* TGT = (float4*)((float*)d_out + N);

  uint8_t* ws = (uint8_t*)d_ws;
  uint32_t* counters = (uint32_t*)ws;                  // 16 u32
  uint32_t* gmaxu = (uint32_t*)(ws + 512);             // 128 u32 (zero-init)
  uint32_t* accum = (uint32_t*)(ws + 1024);            // 32 x 64B slots
  uint32_t* candLbl = (uint32_t*)(ws + 16384);         // CAND_CAP u32 (32 KB)
  uint32_t* pmax = (uint32_t*)(ws + 65536);            // NBm*R u32 (~820 KB)
  size_t off = 65536 + (size_t)NBm * R * 4;
  off = (off + 7) & ~(size_t)7;
  uint64_t* candList = (uint64_t*)(ws + off);
  uint64_t* listF = (uint64_t*)(ws + off + CAND_CAP * 8);
  uint64_t* listB = (uint64_t*)(ws + off + CAND_CAP * 8 + FILT_CAP * 8);

  // Partitionable jax.random.split(key(42), 3): key_j = threefry((0,42),(0,j))
  uint32_t k1a, k1b, k2a, k2b, k3a, k3b;
  tf2x32(0u, 42u, 0u, 0u, k1a, k1b);
  tf2x32(0u, 42u, 0u, 1u, k2a, k2b);
  tf2x32(0u, 42u, 0u, 2u, k3a, k3b);

  hipMemsetAsync(ws, 0, 4096, stream);  // counters + gmaxu + acc; graph-capturable
  k_main<<<NBm, 256, 0, stream>>>(anc, img, gtb, N, R, pmax, gmaxu, LBL, TGT, accum);
  k_gather<<<NBg, 256, 0, stream>>>(anc, img, gtb, N, R, pmax, gmaxu, LBL,
                                    candList, candLbl, listF, listB, counters, accum,
                                    k1a, k1b, k2a, k2b, k3a, k3b);
  k_sel<<<1, 256, 0, stream>>>(LBL, listF, listB, candList, candLbl, counters, accum,
                               R, k3a, k3b);
}

// Round 6
// 129.068 us; speedup vs baseline: 1.6673x; 1.0786x over previous
//
#include <hip/hip_runtime.h>
#include <stdint.h>

#define NGT_MAX 128
#define CAND_CAP 8192
#define CSEL_CAP 512
#define FILT_CAP 16384
#define SUB_CAP 2048

// ws layout (first 4 KB zeroed by hipMemsetAsync):
//   counters @0: [0]=cand cnt, [4]=fg filt cnt, [5]=bg filt cnt
//   gmaxu    @512: 128 u32 (zero-init; fmap never returns 0)
//   acc      @1024: 32 slots x 64B; slot s holds {fgCount, bgCount} at acc[16s..16s+1]

// ---- threefry2x32 (exact JAX semantics) ----
__host__ __device__ inline void tf2x32(uint32_t k0, uint32_t k1, uint32_t c0, uint32_t c1,
                                       uint32_t& o0, uint32_t& o1) {
  uint32_t ks[3] = {k0, k1, k0 ^ k1 ^ 0x1BD11BDAu};
  uint32_t x0 = c0 + ks[0];
  uint32_t x1 = c1 + ks[1];
  const int rot[2][4] = {{13, 15, 26, 6}, {17, 29, 16, 24}};
#pragma unroll
  for (int i = 0; i < 5; ++i) {
#pragma unroll
    for (int j = 0; j < 4; ++j) {
      x0 += x1;
      int r = rot[i & 1][j];
      x1 = (x1 << r) | (x1 >> (32 - r));
      x1 ^= x0;
    }
    x0 += ks[(i + 1) % 3];
    x1 += ks[(i + 2) % 3] + (uint32_t)(i + 1);
  }
  o0 = x0; o1 = x1;
}

// Partitionable threefry: element i uses block (0,i); draw = o0^o1.
// Selection key = (bits>>9, index) lexicographic (stable argsort tiebreak).
__device__ inline uint64_t sel_key(uint32_t i, uint32_t ka, uint32_t kb) {
  uint32_t o0, o1;
  tf2x32(ka, kb, 0u, i, o0, o1);
  uint32_t bits = o0 ^ o1;
  return ((uint64_t)(bits >> 9) << 32) | (uint64_t)i;
}

__device__ inline uint32_t fmap(float v) {
  uint32_t u = __float_as_uint(v);
  return (u & 0x80000000u) ? ~u : (u | 0x80000000u);
}
__device__ inline float funmap(uint32_t m) {
  return (m & 0x80000000u) ? __uint_as_float(m & 0x7FFFFFFFu) : __uint_as_float(~m);
}

// 32-slot spread-accumulator reduce: first wave sums acc slots, result -> sbase[0..1].
// Call with all 256 threads; follow with __syncthreads() at the call site.
__device__ __forceinline__ void acc_reduce(const uint32_t* __restrict__ acc,
                                           uint32_t* sbase) {
  const int t = threadIdx.x;
  if (t < 64) {
    uint32_t f = 0u, g2 = 0u;
    if (t < 32) { f = acc[t * 16]; g2 = acc[t * 16 + 1]; }
#pragma unroll
    for (int o = 32; o > 0; o >>= 1) {
      f += __shfl_down(f, o);
      g2 += __shfl_down(g2, o);
    }
    if (t == 0) { sbase[0] = f; sbase[1] = g2; }
  }
}

// Conservative thresholds from base counts only (baseF <= M1, M2 >= baseB-8192).
__device__ inline void cons_meta(uint32_t baseF, uint32_t baseB, uint32_t* needF,
                                 uint32_t* Tf, uint32_t* needB, uint32_t* Tb) {
  *needF = (baseF > 128u) ? 1u : 0u;
  uint64_t tf = 0, tb = 0;
  if (*needF) {
    tf = (((uint64_t)(128u * 32u)) << 23) / (uint64_t)baseF;
    if (tf > (1u << 23)) tf = (1u << 23);
  }
  uint32_t nfgmin = baseF < 128u ? baseF : 128u;
  uint32_t kbgmax = 256u - nfgmin;
  *needB = (baseB > 8192u + kbgmax) ? 1u : 0u;
  if (*needB) {
    tb = (((uint64_t)(kbgmax * 32u)) << 23) / (uint64_t)(baseB - 8192u);
    if (tb > (1u << 23)) tb = (1u << 23);
  }
  *Tf = (uint32_t)tf;
  *Tb = (uint32_t)tb;
}

__device__ __forceinline__ float iou_ref(const float4& a, float area_a, const float4& gb,
                                         float area_g) {
#pragma clang fp contract(off)
  float iw = fminf(a.z, gb.z) - fmaxf(a.x, gb.x) + 1.0f;
  float ih = fminf(a.w, gb.w) - fmaxf(a.y, gb.y) + 1.0f;
  float inter = fmaxf(iw, 0.0f) * fmaxf(ih, 0.0f);
  return inter / (area_a + area_g - inter);
}

__device__ __forceinline__ float4 tgt_ref(const float4& a, const float4& gb) {
#pragma clang fp contract(off)
  float aw = a.z - a.x + 1.0f;
  float ah = a.w - a.y + 1.0f;
  float acx = a.x + 0.5f * aw;
  float acy = a.y + 0.5f * ah;
  float gw = gb.z - gb.x + 1.0f;
  float gh = gb.w - gb.y + 1.0f;
  float gcx = gb.x + 0.5f * gw;
  float gcy = gb.y + 0.5f * gh;
  return make_float4((gcx - acx) / aw, (gcy - acy) / ah, logf(gw / aw), logf(gh / ah));
}

// IoU pass, 2 ANCHORS PER LANE x 2 HALF-LANES PER ANCHOR: lane = 32*h + al;
// lane handles anchors (i0, i0+32) vs the 50 gts of half h. Each sgt load,
// address calc, and DPP column-reduce is amortized over 2 IoU pairs (column
// value = fmax(v0,v1) before the quad reduce -- max over anchors commutes).
// 1024 blocks x 256 threads, 256 anchors/block. sq init to -1 is REQUIRED:
// each 16-row covers only one g-half (round-5 lesson).
__global__ void __launch_bounds__(256)
k_main(const float4* __restrict__ anc, const float* __restrict__ img,
       const float4* __restrict__ gt, int N, int R,
       uint32_t* __restrict__ pmax, uint32_t* __restrict__ gmaxu,
       float* __restrict__ LBL, float4* __restrict__ TGT,
       uint32_t* __restrict__ acc) {
  __shared__ float4 sgt[NGT_MAX];
  __shared__ float sarea[NGT_MAX];
  __shared__ float sq[16 * 101];  // 6.5 KB
  __shared__ uint32_t scnt[2];
  const int t = threadIdx.x, b = blockIdx.x;
  if (t < 2) scnt[t] = 0u;
  if (t < NGT_MAX) {
    float4 g = (t < R) ? gt[t] : make_float4(0.0f, 0.0f, -1.0f, -1.0f);
    sgt[t] = g;
    {
#pragma clang fp contract(off)
      sarea[t] = (t < R) ? ((g.z - g.x + 1.0f) * (g.w - g.y + 1.0f)) : 0.0f;
    }
  }
  for (int j = t; j < 16 * 101; j += 256) sq[j] = -1.0f;
  __syncthreads();
  const int lane = t & 63, wid = t >> 6;
  const int h = lane >> 5;       // g-half
  const int al = lane & 31;      // anchor slot within wave
  const int p = lane & 3;
  const int i0 = b * 256 + wid * 64 + al;
  const int i1 = i0 + 32;
  const int gbase = 50 * h;
  const float H = img[0], W = img[1];
  float4 a0 = anc[i0];
  float4 a1 = anc[i1];
  bool in0 = (a0.x >= 0.0f) && (a0.y >= 0.0f) && (a0.z < W) && (a0.w < H);
  bool in1 = (a1.x >= 0.0f) && (a1.y >= 0.0f) && (a1.z < W) && (a1.w < H);
  float ar0, ar1;
  {
#pragma clang fp contract(off)
    ar0 = (a0.z - a0.x + 1.0f) * (a0.w - a0.y + 1.0f);
    ar1 = (a1.z - a1.x + 1.0f) * (a1.w - a1.y + 1.0f);
  }
  if (!in0) ar0 = __uint_as_float(0x7FC00000u);  // NaN-poison; v_max drops NaN
  if (!in1) ar1 = __uint_as_float(0x7FC00000u);
  const bool b1 = (p == 1), b2 = (p == 2), b3 = (p == 3);
  float part[13];
  float vm0 = -1.0f, vm1 = -1.0f;
#pragma unroll
  for (int s = 0; s < 13; ++s) {
    float v2q[4];
#pragma unroll
    for (int k = 0; k < 4; ++k) {
      const int j = 4 * s + k;
      if (j < 50) {  // compile-time; degenerate pad covers g >= R
        const int g = gbase + j;
        float4 gb = sgt[g];
        float ag = sarea[g];
        float v0 = iou_ref(a0, ar0, gb, ag);
        float v1 = iou_ref(a1, ar1, gb, ag);
        vm0 = fmaxf(vm0, v0);
        vm1 = fmaxf(vm1, v1);
        float v = fmaxf(v0, v1);  // column contribution: max over this lane's anchors
        int d1 = __builtin_amdgcn_mov_dpp(__float_as_int(v), 0xB1, 0xF, 0xF, true);
        float v1q = fmaxf(v, __int_as_float(d1));
        int d2 = __builtin_amdgcn_mov_dpp(__float_as_int(v1q), 0x4E, 0xF, 0xF, true);
        v2q[k] = fmaxf(v1q, __int_as_float(d2));
      } else {
        v2q[k] = -1.0f;
      }
    }
    float pp = v2q[0];
    pp = b1 ? v2q[1] : pp;
    pp = b2 ? v2q[2] : pp;
    pp = b3 ? v2q[3] : pp;
    part[s] = pp;
  }
  // per-anchor vmax: combine the two halves (lane ^ 32)
  vm0 = fmaxf(vm0, __shfl_xor(vm0, 32));
  vm1 = fmaxf(vm1, __shfl_xor(vm1, 32));
  float lbl0 = -1.0f, lbl1 = -1.0f;
  if (in0) {
    if (vm0 < 0.3f) lbl0 = 0.0f;
    if (vm0 >= 0.7f) lbl0 = 1.0f;
  }
  if (in1) {
    if (vm1 < 0.3f) lbl1 = 0.0f;
    if (vm1 >= 0.7f) lbl1 = 1.0f;
  }
  // count each anchor once (lower 32 lanes; both halves hold identical labels)
  uint32_t nf = (uint32_t)__popcll(__ballot(lbl0 == 1.0f) & 0xFFFFFFFFull)
              + (uint32_t)__popcll(__ballot(lbl1 == 1.0f) & 0xFFFFFFFFull);
  uint32_t nb = (uint32_t)__popcll(__ballot(lbl0 == 0.0f) & 0xFFFFFFFFull)
              + (uint32_t)__popcll(__ballot(lbl1 == 0.0f) & 0xFFFFFFFFull);
  if (lane == 0) {
    atomicAdd(&scnt[0], nf);
    atomicAdd(&scnt[1], nb);
  }
  if (h == 0) {
    LBL[i0] = lbl0;
    LBL[i1] = lbl1;
    float4 o0 = make_float4(0.f, 0.f, 0.f, 0.f);
    float4 o1 = make_float4(0.f, 0.f, 0.f, 0.f);
    if (in0) {
      int idx = (int)vm0;  // faithful astype(int32) of max_ov
      idx = idx < 0 ? 0 : (idx > R - 1 ? R - 1 : idx);
      o0 = tgt_ref(a0, sgt[idx]);
    }
    if (in1) {
      int idx = (int)vm1;
      idx = idx < 0 ? 0 : (idx > R - 1 ? R - 1 : idx);
      o1 = tgt_ref(a1, sgt[idx]);
    }
    TGT[i0] = o0;
    TGT[i1] = o1;
  }
  // epilogue: cross-quad (4 quads per 16-row) reduce in registers
#pragma unroll
  for (int s = 0; s < 13; ++s) {
    float v = part[s];
    int x = __builtin_amdgcn_mov_dpp(__float_as_int(v), 0x114, 0xF, 0xF, true);  // shr:4
    v = fmaxf(v, __int_as_float(x));
    x = __builtin_amdgcn_mov_dpp(__float_as_int(v), 0x118, 0xF, 0xF, true);      // shr:8
    v = fmaxf(v, __int_as_float(x));
    part[s] = v;
  }
  const int r = t >> 4;
  if ((t & 15) >= 12) {  // lanes 12..15 hold the 4-quad max at position p=(t&15)-12
#pragma unroll
    for (int s = 0; s < 13; ++s) {
      const int j = 4 * s + p;
      if (j < 50) sq[r * 101 + gbase + j] = part[s];
    }
  }
  __syncthreads();
  if (t < R) {
    float m = -1.0f;
#pragma unroll 8
    for (int r2 = 0; r2 < 16; ++r2) m = fmaxf(m, sq[r2 * 101 + t]);  // drops NaN
    uint32_t u = fmap(m);
    pmax[b * R + t] = u;
    if (u > gmaxu[t]) atomicMax(&gmaxu[t], u);  // stale-low guard read: still correct
  }
  if (t == 0) {
    const uint32_t slot = (uint32_t)(b & 31) * 16u;  // own 64B line per slot
    atomicAdd(&acc[slot], scnt[0]);      // fg partial
    atomicAdd(&acc[slot + 1], scnt[1]);  // bg partial
  }
}

// Gather (256 anchors/block = 1 main-block now): tie detection via ONE pmax row
// vs gmax + bit-exact IoU recompute; provisional keep-all flip; conservative
// prefilter; block-staged appends. Base counts from the 32-slot accumulator.
__global__ void __launch_bounds__(256)
k_gather(const float4* __restrict__ anc, const float* __restrict__ img,
         const float4* __restrict__ gt, int N, int R,
         const uint32_t* __restrict__ pmax, const uint32_t* __restrict__ gmaxu,
         float* __restrict__ LBL,
         uint64_t* __restrict__ candList, uint32_t* __restrict__ candLbl,
         uint64_t* __restrict__ listF, uint64_t* __restrict__ listB,
         uint32_t* __restrict__ counters, const uint32_t* __restrict__ acc,
         uint32_t k1a, uint32_t k1b, uint32_t k2a, uint32_t k2b,
         uint32_t k3a, uint32_t k3b) {
  __shared__ int tg[NGT_MAX];
  __shared__ float tgm[NGT_MAX];
  __shared__ float4 sgt[NGT_MAX];
  __shared__ float sarea[NGT_MAX];
  __shared__ uint64_t cbuf[256];
  __shared__ uint32_t cbufL[256];
  __shared__ uint64_t bufF[256], bufB[256];
  __shared__ uint32_t sbase[2];
  __shared__ uint32_t cC, cF, cB, oC, oF, oB;
  __shared__ int tcnt;
  const int t = threadIdx.x, b = blockIdx.x;
  if (t == 0) { tcnt = 0; cC = 0u; cF = 0u; cB = 0u; }
  acc_reduce(acc, sbase);
  if (t < R) {
    float4 g = gt[t];
    sgt[t] = g;
    {
#pragma clang fp contract(off)
      sarea[t] = (g.z - g.x + 1.0f) * (g.w - g.y + 1.0f);
    }
  }
  __syncthreads();
  const uint32_t baseF = sbase[0];
  const uint32_t baseB = sbase[1];
  uint32_t needF, Tf, needB, Tb;
  cons_meta(baseF, baseB, &needF, &Tf, &needB, &Tb);
  if (t < R) {
    uint32_t gm = gmaxu[t];
    if (pmax[b * R + t] == gm) {
      int pp = atomicAdd(&tcnt, 1);
      tg[pp] = t;
      tgm[pp] = funmap(gm);
    }
  }
  __syncthreads();
  const int C0 = tcnt;
  const int i = b * 256 + t;
  const float H = img[0], W = img[1];
  float old = LBL[i];
  bool isc = false;
  if (C0 > 0) {
    float4 a = anc[i];
    bool inside = (a.x >= 0.0f) && (a.y >= 0.0f) && (a.z < W) && (a.w < H);
    if (inside) {
      float area_a;
      {
#pragma clang fp contract(off)
        area_a = (a.z - a.x + 1.0f) * (a.w - a.y + 1.0f);
      }
      for (int j = 0; j < C0; ++j) {
        int g = tg[j];
        float v = iou_ref(a, area_a, sgt[g], sarea[g]);  // bit-identical to k_main
        isc = isc || (v == tgm[j]);
      }
    }
  }
  if (isc) {
    uint32_t code = (old == 1.0f) ? 2u : ((old == 0.0f) ? 1u : 0u);
    uint32_t pp = atomicAdd(&cC, 1u);
    cbuf[pp] = sel_key((uint32_t)i, k1a, k1b);
    cbufL[pp] = code;
  }
  float l1 = isc ? 1.0f : old;  // provisional keep-all (k_sel fixes if C > R)
  float out = l1;
  if (l1 == 1.0f) {
    uint64_t key = sel_key((uint32_t)i, k2a, k2b);
    if (needF && (uint32_t)(key >> 32) >= Tf) {
      out = -1.0f;
    } else {
      uint32_t pp = atomicAdd(&cF, 1u);
      bufF[pp] = key;
    }
  } else if (l1 == 0.0f) {
    uint64_t key = sel_key((uint32_t)i, k3a, k3b);
    if (needB && (uint32_t)(key >> 32) >= Tb) {
      out = -1.0f;
    } else {
      uint32_t pp = atomicAdd(&cB, 1u);
      bufB[pp] = key;
    }
  }
  LBL[i] = out;
  __syncthreads();
  if (t == 0 && cC) oC = atomicAdd(&counters[0], cC);
  if (t == 64 && cF) oF = atomicAdd(&counters[4], cF);
  if (t == 128 && cB) oB = atomicAdd(&counters[5], cB);
  __syncthreads();
  for (uint32_t j = t; j < cC; j += 256) {
    uint32_t pp = oC + j;
    if (pp < CAND_CAP) { candList[pp] = cbuf[j]; candLbl[pp] = cbufL[j]; }
  }
  for (uint32_t j = t; j < cF; j += 256) {
    uint32_t pp = oF + j;
    if (pp < FILT_CAP) listF[pp] = bufF[j];
  }
  for (uint32_t j = t; j < cB; j += 256) {
    uint32_t pp = oB + j;
    if (pp < FILT_CAP) listB[pp] = bufB[j];
  }
}

// exact k-smallest among list (all keys < T): 256-bin hist + scan + in-bin rank,
// with optional drop-index exclusion.
__device__ __forceinline__ void do_select(const uint64_t* list, uint32_t Mf, uint32_t k,
                                          uint32_t T, float* LBL, uint32_t* h,
                                          uint32_t* c0, uint32_t* c1, uint64_t* sub,
                                          uint32_t* scal, const uint32_t* drop,
                                          uint32_t nd) {
  const int t = threadIdx.x;
  if (Mf <= k) return;
  int bl = (T > 1u) ? (32 - __clz(T - 1u)) : 0;
  int shift = bl > 8 ? bl - 8 : 0;
  h[t] = 0u;
  if (t == 0) { scal[0] = 0u; scal[1] = 0u; scal[2] = 0u; }
  __syncthreads();
  for (uint32_t j = t; j < Mf; j += 256) {
    uint64_t key = list[j];
    bool skip = false;
    for (uint32_t d = 0; d < nd; ++d) skip = skip || (drop[d] == (uint32_t)key);
    if (!skip) atomicAdd(&h[((uint32_t)(key >> 32)) >> shift], 1u);
  }
  __syncthreads();
  c0[t] = h[t];
  __syncthreads();
  uint32_t* s = c0;
  uint32_t* d2 = c1;
  for (int dd = 1; dd < 256; dd <<= 1) {
    uint32_t v = s[t];
    if (t >= dd) v += s[t - dd];
    d2[t] = v;
    __syncthreads();
    uint32_t* tmp = s; s = d2; d2 = tmp;
  }
  uint32_t inc = s[t];
  uint32_t exc = inc - h[t];
  if (exc < k && inc >= k) { scal[1] = (uint32_t)t; scal[2] = k - exc; }
  __syncthreads();
  const uint32_t binb = scal[1], rneed = scal[2];
  for (uint32_t j = t; j < Mf; j += 256) {
    uint64_t key = list[j];
    bool skip = false;
    for (uint32_t d = 0; d < nd; ++d) skip = skip || (drop[d] == (uint32_t)key);
    if (skip) continue;
    uint32_t bin = ((uint32_t)(key >> 32)) >> shift;
    if (bin > binb) {
      LBL[(uint32_t)key] = -1.0f;
    } else if (bin == binb) {
      uint32_t pp = atomicAdd(&scal[0], 1u);
      if (pp < SUB_CAP) sub[pp] = key;
    }
  }
  __syncthreads();
  uint32_t c = scal[0] < SUB_CAP ? scal[0] : SUB_CAP;
  for (uint32_t s2 = t; s2 < c; s2 += 256) {
    uint64_t key = sub[s2];
    uint32_t rank = 0u;
    for (uint32_t j = 0; j < c; ++j) rank += (sub[j] < key) ? 1u : 0u;
    if (rank >= rneed) LBL[(uint32_t)key] = -1.0f;
  }
  __syncthreads();
}

// Single block: exact meta from the 32-slot accumulator; undo wrong provisional
// flips if C > R; exact top-k selects.
__global__ void __launch_bounds__(256)
k_sel(float* __restrict__ LBL, uint64_t* __restrict__ listF,
      uint64_t* __restrict__ listB, const uint64_t* __restrict__ candList,
      const uint32_t* __restrict__ candLbl,
      uint32_t* __restrict__ counters, const uint32_t* __restrict__ acc, int R,
      uint32_t k3a, uint32_t k3b) {
  __shared__ uint64_t ck[CSEL_CAP];
  __shared__ uint32_t cc[CSEL_CAP];
  __shared__ uint32_t drop[256];
  __shared__ uint32_t h[256], c0s[256], c1s[256];
  __shared__ uint64_t sub[SUB_CAP];
  __shared__ uint32_t scal[8];
  __shared__ uint32_t sbase[2];
  const int t = threadIdx.x;
  if (t < 8) scal[t] = 0u;
  acc_reduce(acc, sbase);
  uint32_t C = counters[0];
  if (C > CSEL_CAP) C = CSEL_CAP;
  for (uint32_t s = t; s < C; s += 256) { ck[s] = candList[s]; cc[s] = candLbl[s]; }
  __syncthreads();
  const uint32_t baseF = sbase[0];
  const uint32_t baseB = sbase[1];
  uint32_t needFc, TfC, needBc, TbC;
  cons_meta(baseF, baseB, &needFc, &TfC, &needBc, &TbC);
  const uint32_t MfB0 = counters[5] < FILT_CAP ? counters[5] : FILT_CAP;
  for (uint32_t e = t; e < C; e += 256) {
    uint64_t key = ck[e];
    bool keep = true;
    if (C > (uint32_t)R) {
      uint32_t rank = 0;
      for (uint32_t j = 0; j < C; ++j) rank += (ck[j] < key) ? 1u : 0u;
      keep = (rank < (uint32_t)R);
    }
    uint32_t code = cc[e];
    uint32_t idx = (uint32_t)key;
    if (keep) {
      if (code != 2u) atomicAdd(&scal[4], 1u);  // fgflips
      if (code == 1u) atomicAdd(&scal[5], 1u);  // bgflips
    } else if (code != 2u) {
      uint32_t pp = atomicAdd(&scal[3], 1u);  // nDrop
      if (pp < 256) drop[pp] = idx;
      if (code == 0u) {
        LBL[idx] = -1.0f;
      } else {  // restore to bg flow
        uint64_t key3 = sel_key(idx, k3a, k3b);
        if (needBc && (uint32_t)(key3 >> 32) >= TbC) {
          LBL[idx] = -1.0f;
        } else {
          uint32_t qq = atomicAdd(&scal[6], 1u);  // nAddB
          if (MfB0 + qq < FILT_CAP) listB[MfB0 + qq] = key3;
          LBL[idx] = 0.0f;
        }
      }
    }
  }
  __syncthreads();
  const uint32_t fgflips = scal[4], bgflips = scal[5];
  const uint32_t nDrop = scal[3] < 256u ? scal[3] : 256u;
  const uint32_t nAdd = scal[6];
  const uint32_t M1 = baseF + fgflips;
  const uint32_t M2 = baseB - bgflips;
  const uint32_t nfg = M1 < 128u ? M1 : 128u;
  const uint32_t kbg = 256u - nfg;
  if (M1 > 128u) {
    uint32_t MfF = counters[4] < FILT_CAP ? counters[4] : FILT_CAP;
    uint32_t TF = needFc ? TfC : (1u << 23);
    do_select(listF, MfF, 128u, TF, LBL, h, c0s, c1s, sub, scal, drop, nDrop);
  }
  if (M2 > kbg) {
    uint32_t MfB = MfB0 + nAdd;
    if (MfB > FILT_CAP) MfB = FILT_CAP;
    uint32_t TB = needBc ? TbC : (1u << 23);
    do_select(listB, MfB, kbg, TB, LBL, h, c0s, c1s, sub, scal, drop, 0u);
  }
}

extern "C" void kernel_launch(void* const* d_in, const int* in_sizes, int n_in,
                              void* d_out, int out_size, void* d_ws, size_t ws_size,
                              hipStream_t stream) {
  (void)n_in; (void)out_size; (void)ws_size;
  const int N = in_sizes[0] / 4;  // 262144 anchors (multiple of 256)
  const int R = in_sizes[2] / 4;  // 100 gt boxes (51..100 assumed by the h-split)
  const int NBm = N / 256;        // k_main blocks (1024; 256 anchors each)
  const int NBg = N / 256;        // k_gather blocks (1024)
  const float4* anc = (const float4*)d_in[0];
  const float* img = (const float*)d_in[1];
  const float4* gtb = (const float4*)d_in[2];
  float* LBL = (float*)d_out;
  float4* TGT = (float4*)((float*)d_out + N);

  uint8_t* ws = (uint8_t*)d_ws;
  uint32_t* counters = (uint32_t*)ws;                  // 16 u32
  uint32_t* gmaxu = (uint32_t*)(ws + 512);             // 128 u32 (zero-init)
  uint32_t* accum = (uint32_t*)(ws + 1024);            // 32 x 64B slots
  uint32_t* candLbl = (uint32_t*)(ws + 16384);         // CAND_CAP u32 (32 KB)
  uint32_t* pmax = (uint32_t*)(ws + 65536);            // NBm*R u32 (~410 KB)
  size_t off = 65536 + (size_t)NBm * R * 4;
  off = (off + 7) & ~(size_t)7;
  uint64_t* candList = (uint64_t*)(ws + off);
  uint64_t* listF = (uint64_t*)(ws + off + CAND_CAP * 8);
  uint64_t* listB = (uint64_t*)(ws + off + CAND_CAP * 8 + FILT_CAP * 8);

  // Partitionable jax.random.split(key(42), 3): key_j = threefry((0,42),(0,j))
  uint32_t k1a, k1b, k2a, k2b, k3a, k3b;
  tf2x32(0u, 42u, 0u, 0u, k1a, k1b);
  tf2x32(0u, 42u, 0u, 1u, k2a, k2b);
  tf2x32(0u, 42u, 0u, 2u, k3a, k3b);

  hipMemsetAsync(ws, 0, 4096, stream);  // counters + gmaxu + acc; graph-capturable
  k_main<<<NBm, 256, 0, stream>>>(anc, img, gtb, N, R, pmax, gmaxu, LBL, TGT, accum);
  k_gather<<<NBg, 256, 0, stream>>>(anc, img, gtb, N, R, pmax, gmaxu, LBL,
                                    candList, candLbl, listF, listB, counters, accum,
                                    k1a, k1b, k2a, k2b, k3a, k3b);
  k_sel<<<1, 256, 0, stream>>>(LBL, listF, listB, candList, candLbl, counters, accum,
                               R, k3a, k3b);
}